// Round 1
// baseline (989.467 us; speedup 1.0000x reference)
//
#include <hip/hip_runtime.h>
#include <math.h>

#define B_ 8
#define SQn 1024
#define SKn 1024
#define Dn 1024
#define Hn 8
#define DHn 128

// workspace float offsets
#define OFF_CQ 0
#define OFF_SQ 65536
#define OFF_CK 131072
#define OFF_SK 196608
#define OFF_PC 262144
#define OFF_PS 327680
#define OFF_CV 393216
#define OFF_SV 401408
#define OFF_M  409600
#define OFF_DEN 540672
#define OFF_X  606208
#define OFF_H1 8994816
// total: 17383424 floats = 66.3 MiB

// ---------------- prep: per-head scalar q/k trig ----------------
__global__ void k_trig(const float* __restrict__ key_in, const float* __restrict__ query_in,
                       const float* __restrict__ Wk, const float* __restrict__ Wq,
                       float* __restrict__ ws) {
    int idx = blockIdx.x * blockDim.x + threadIdx.x;   // 131072 threads
    const int n = B_ * SQn * Hn;                       // 65536
    if (idx < n) {
        int h = idx & 7, bs = idx >> 3;
        float v = query_in[bs] * Wq[h];
        ws[OFF_CQ + idx] = cosf(v);
        ws[OFF_SQ + idx] = sinf(v);
    } else {
        int i2 = idx - n;
        int h = i2 & 7, bs = i2 >> 3;
        float v = key_in[bs] * Wk[h];
        ws[OFF_CK + i2] = cosf(v);
        ws[OFF_SK + i2] = sinf(v);
    }
}

// ---------------- P[b,h,i] = sum_k trig(k)*value_in[b,k,i] ----------------
__global__ void k_phase(const float* __restrict__ value_in, const float* __restrict__ ck,
                        const float* __restrict__ sk, float* __restrict__ Pc,
                        float* __restrict__ Ps) {
    __shared__ __align__(16) float ckk[1024];
    __shared__ __align__(16) float skk[1024];
    const int b = blockIdx.x, it = blockIdx.y, kc = blockIdx.z;
    const int tid = threadIdx.x;
    const int base = (b * SKn + kc * 128) * Hn;
    *(float4*)&ckk[tid * 4] = *(const float4*)&ck[base + tid * 4];
    *(float4*)&skk[tid * 4] = *(const float4*)&sk[base + tid * 4];
    __syncthreads();
    const int i = it * 256 + tid;
    float aC[8] = {0,0,0,0,0,0,0,0}, aS[8] = {0,0,0,0,0,0,0,0};
    const float* vp = value_in + (size_t)(b * SKn + kc * 128) * Dn + i;
    for (int kk = 0; kk < 128; ++kk) {
        float v = vp[(size_t)kk * Dn];
        float4 c0 = *(const float4*)&ckk[kk * 8];
        float4 c1 = *(const float4*)&ckk[kk * 8 + 4];
        float4 s0 = *(const float4*)&skk[kk * 8];
        float4 s1 = *(const float4*)&skk[kk * 8 + 4];
        aC[0] = fmaf(v, c0.x, aC[0]); aC[1] = fmaf(v, c0.y, aC[1]);
        aC[2] = fmaf(v, c0.z, aC[2]); aC[3] = fmaf(v, c0.w, aC[3]);
        aC[4] = fmaf(v, c1.x, aC[4]); aC[5] = fmaf(v, c1.y, aC[5]);
        aC[6] = fmaf(v, c1.z, aC[6]); aC[7] = fmaf(v, c1.w, aC[7]);
        aS[0] = fmaf(v, s0.x, aS[0]); aS[1] = fmaf(v, s0.y, aS[1]);
        aS[2] = fmaf(v, s0.z, aS[2]); aS[3] = fmaf(v, s0.w, aS[3]);
        aS[4] = fmaf(v, s1.x, aS[4]); aS[5] = fmaf(v, s1.y, aS[5]);
        aS[6] = fmaf(v, s1.z, aS[6]); aS[7] = fmaf(v, s1.w, aS[7]);
    }
    #pragma unroll
    for (int h = 0; h < 8; ++h) {
        atomicAdd(&Pc[(b * Hn + h) * Dn + i], aC[h]);
        atomicAdd(&Ps[(b * Hn + h) * Dn + i], aS[h]);
    }
}

// ---------------- Cv/Sv[b,h,d] = sum_i P[b,h,i]*Wv[i, h*128+d] ----------------
__global__ void k_cv(const float* __restrict__ Pc, const float* __restrict__ Ps,
                     const float* __restrict__ Wv, float* __restrict__ Cv,
                     float* __restrict__ Sv) {
    const int bh = blockIdx.x;
    const int h = bh & 7;
    const int d = threadIdx.x;  // 128
    float ac = 0.f, as = 0.f;
    const float* wp = Wv + h * DHn + d;
    const float* pc = Pc + bh * Dn;
    const float* ps = Ps + bh * Dn;
    #pragma unroll 4
    for (int i = 0; i < Dn; ++i) {
        float w = wp[(size_t)i * Dn];
        ac = fmaf(pc[i], w, ac);
        as = fmaf(ps[i], w, as);
    }
    Cv[bh * DHn + d] = ac;
    Sv[bh * DHn + d] = as;
}

// ---------------- M[b,t,j]: t=h -> Cv@Wf slice, t=8+h -> Sv@Wf slice ----------------
__global__ void k_m(const float* __restrict__ Cv, const float* __restrict__ Sv,
                    const float* __restrict__ Wf, float* __restrict__ M) {
    const int bh = blockIdx.x;
    const int b = bh >> 3, h = bh & 7;
    const int j = threadIdx.x * 4;
    float4 ac = {0,0,0,0}, as = {0,0,0,0};
    #pragma unroll 4
    for (int d = 0; d < DHn; ++d) {
        float cv = Cv[bh * DHn + d];
        float sv = Sv[bh * DHn + d];
        float4 w = *(const float4*)&Wf[(size_t)(h * DHn + d) * Dn + j];
        ac.x = fmaf(cv, w.x, ac.x); ac.y = fmaf(cv, w.y, ac.y);
        ac.z = fmaf(cv, w.z, ac.z); ac.w = fmaf(cv, w.w, ac.w);
        as.x = fmaf(sv, w.x, as.x); as.y = fmaf(sv, w.y, as.y);
        as.z = fmaf(sv, w.z, as.z); as.w = fmaf(sv, w.w, as.w);
    }
    *(float4*)&M[(size_t)(b * 16 + h) * Dn + j] = ac;
    *(float4*)&M[(size_t)(b * 16 + 8 + h) * Dn + j] = as;
}

// ---------------- denom[b,q,h] = sum_k |cq*ck + sq*sk| + eps ----------------
__global__ void k_denom(const float* __restrict__ ws, float* __restrict__ den) {
    __shared__ __align__(16) float ckk[8][132];
    __shared__ __align__(16) float skk[8][132];
    const int b = blockIdx.x, qt = blockIdx.y;
    const int tid = threadIdx.x;
    const int qq = tid >> 3, h = tid & 7;
    const int q = qt * 32 + qq;
    const float cqv = ws[OFF_CQ + (b * SQn + q) * Hn + h];
    const float sqv = ws[OFF_SQ + (b * SQn + q) * Hn + h];
    float acc = 0.f;
    for (int kc = 0; kc < 8; ++kc) {
        __syncthreads();
        const int base = (b * SKn + kc * 128) * Hn;
        float4 c4 = *(const float4*)&ws[OFF_CK + base + tid * 4];
        float4 s4 = *(const float4*)&ws[OFF_SK + base + tid * 4];
        #pragma unroll
        for (int u = 0; u < 4; ++u) {
            int f = tid * 4 + u;
            ckk[f & 7][f >> 3] = ((const float*)&c4)[u];
            skk[f & 7][f >> 3] = ((const float*)&s4)[u];
        }
        __syncthreads();
        #pragma unroll
        for (int kv = 0; kv < 32; ++kv) {
            float4 c = *(const float4*)&ckk[h][kv * 4];
            float4 s = *(const float4*)&skk[h][kv * 4];
            acc += fabsf(cqv * c.x + sqv * s.x);
            acc += fabsf(cqv * c.y + sqv * s.y);
            acc += fabsf(cqv * c.z + sqv * s.z);
            acc += fabsf(cqv * c.w + sqv * s.w);
        }
    }
    den[(b * SQn + q) * Hn + h] = acc + 1e-6f;
}

// ---------------- block LayerNorm stats helper ----------------
__device__ inline void block_ln_stats(float lsum, float lsq, float* red,
                                      float& mean, float& rstd) {
    #pragma unroll
    for (int off = 32; off; off >>= 1) {
        lsum += __shfl_xor(lsum, off);
        lsq  += __shfl_xor(lsq, off);
    }
    const int wid = threadIdx.x >> 6;
    if ((threadIdx.x & 63) == 0) { red[wid * 2] = lsum; red[wid * 2 + 1] = lsq; }
    __syncthreads();
    if (threadIdx.x == 0) {
        float s  = red[0] + red[2] + red[4] + red[6];
        float ss = red[1] + red[3] + red[5] + red[7];
        float m = s * (1.0f / Dn);
        red[8] = m;
        red[9] = rsqrtf(ss * (1.0f / Dn) - m * m + 1e-5f);
    }
    __syncthreads();
    mean = red[8];
    rstd = red[9];
}

// ---------------- x = LN(residual + rank16-combine + bf) ----------------
__global__ void k_x(const float* __restrict__ residual, const float* __restrict__ bf,
                    const float* __restrict__ g1, const float* __restrict__ b1,
                    const float* __restrict__ ws, float* __restrict__ X) {
    __shared__ float lcoef[16];
    __shared__ float red[12];
    const int bq = blockIdx.x;       // b*SQ + q
    const int b = bq >> 10;
    const int tid = threadIdx.x;
    if (tid < 8) {
        float dinv = 1.0f / ws[OFF_DEN + bq * Hn + tid];
        lcoef[tid]     = ws[OFF_CQ + bq * Hn + tid] * dinv;
        lcoef[8 + tid] = ws[OFF_SQ + bq * Hn + tid] * dinv;
    }
    __syncthreads();
    const int j = tid * 4;
    float4 acc = *(const float4*)&bf[j];
    const float* Mp = ws + OFF_M + (size_t)b * 16 * Dn + j;
    #pragma unroll
    for (int t = 0; t < 16; ++t) {
        float cf = lcoef[t];
        float4 m4 = *(const float4*)&Mp[(size_t)t * Dn];
        acc.x = fmaf(cf, m4.x, acc.x); acc.y = fmaf(cf, m4.y, acc.y);
        acc.z = fmaf(cf, m4.z, acc.z); acc.w = fmaf(cf, m4.w, acc.w);
    }
    float4 r = *(const float4*)&residual[(size_t)bq * Dn + j];
    acc.x += r.x; acc.y += r.y; acc.z += r.z; acc.w += r.w;
    float lsum = acc.x + acc.y + acc.z + acc.w;
    float lsq = acc.x * acc.x + acc.y * acc.y + acc.z * acc.z + acc.w * acc.w;
    float mean, rstd;
    block_ln_stats(lsum, lsq, red, mean, rstd);
    float4 g = *(const float4*)&g1[j];
    float4 be = *(const float4*)&b1[j];
    float4 o;
    o.x = (acc.x - mean) * rstd * g.x + be.x;
    o.y = (acc.y - mean) * rstd * g.y + be.y;
    o.z = (acc.z - mean) * rstd * g.z + be.z;
    o.w = (acc.w - mean) * rstd * g.w + be.w;
    *(float4*)&X[(size_t)bq * Dn + j] = o;
}

// ---------------- fp32 SGEMM: C = act(A[8192,1024] @ W[1024,1024] + bias) ----------------
#define BM 128
#define BN 128
#define BK 8
__global__ __launch_bounds__(256) void sgemm(const float* __restrict__ A,
                                             const float* __restrict__ W,
                                             const float* __restrict__ bias,
                                             float* __restrict__ C, int relu) {
    __shared__ __align__(16) float As[BK][BM + 4];
    __shared__ __align__(16) float Bs[BK][BN + 4];
    const int tid = threadIdx.x;
    const int m0 = blockIdx.x * BM;
    const int n0 = blockIdx.y * BN;
    const int tx = tid & 15, ty = tid >> 4;
    const int arow = tid >> 1, acol = (tid & 1) * 4;
    const int brow = tid >> 5, bcol = (tid & 31) * 4;
    float acc[8][8];
    #pragma unroll
    for (int i = 0; i < 8; ++i)
        #pragma unroll
        for (int jj = 0; jj < 8; ++jj) acc[i][jj] = 0.f;

    for (int k0 = 0; k0 < 1024; k0 += BK) {
        float4 av = *(const float4*)&A[(size_t)(m0 + arow) * 1024 + k0 + acol];
        float4 bv = *(const float4*)&W[(size_t)(k0 + brow) * 1024 + n0 + bcol];
        __syncthreads();
        As[acol + 0][arow] = av.x;
        As[acol + 1][arow] = av.y;
        As[acol + 2][arow] = av.z;
        As[acol + 3][arow] = av.w;
        *(float4*)&Bs[brow][bcol] = bv;
        __syncthreads();
        #pragma unroll
        for (int kk = 0; kk < BK; ++kk) {
            float4 a0 = *(const float4*)&As[kk][ty * 8];
            float4 a1 = *(const float4*)&As[kk][ty * 8 + 4];
            float4 b0 = *(const float4*)&Bs[kk][tx * 8];
            float4 b1 = *(const float4*)&Bs[kk][tx * 8 + 4];
            float a[8] = {a0.x, a0.y, a0.z, a0.w, a1.x, a1.y, a1.z, a1.w};
            float bb[8] = {b0.x, b0.y, b0.z, b0.w, b1.x, b1.y, b1.z, b1.w};
            #pragma unroll
            for (int i = 0; i < 8; ++i)
                #pragma unroll
                for (int jj = 0; jj < 8; ++jj)
                    acc[i][jj] = fmaf(a[i], bb[jj], acc[i][jj]);
        }
    }
    float4 bs0 = *(const float4*)&bias[n0 + tx * 8];
    float4 bs1 = *(const float4*)&bias[n0 + tx * 8 + 4];
    #pragma unroll
    for (int i = 0; i < 8; ++i) {
        const int row = m0 + ty * 8 + i;
        float4 c0, c1;
        c0.x = acc[i][0] + bs0.x; c0.y = acc[i][1] + bs0.y;
        c0.z = acc[i][2] + bs0.z; c0.w = acc[i][3] + bs0.w;
        c1.x = acc[i][4] + bs1.x; c1.y = acc[i][5] + bs1.y;
        c1.z = acc[i][6] + bs1.z; c1.w = acc[i][7] + bs1.w;
        if (relu) {
            c0.x = fmaxf(c0.x, 0.f); c0.y = fmaxf(c0.y, 0.f);
            c0.z = fmaxf(c0.z, 0.f); c0.w = fmaxf(c0.w, 0.f);
            c1.x = fmaxf(c1.x, 0.f); c1.y = fmaxf(c1.y, 0.f);
            c1.z = fmaxf(c1.z, 0.f); c1.w = fmaxf(c1.w, 0.f);
        }
        *(float4*)&C[(size_t)row * 1024 + n0 + tx * 8] = c0;
        *(float4*)&C[(size_t)row * 1024 + n0 + tx * 8 + 4] = c1;
    }
}

// ---------------- out = LN(x + mlp_out, g2, b2) ----------------
__global__ void k_final(const float* __restrict__ X, const float* __restrict__ Y,
                        const float* __restrict__ g2, const float* __restrict__ b2,
                        float* __restrict__ out) {
    __shared__ float red[12];
    const int bq = blockIdx.x;
    const int tid = threadIdx.x;
    const int j = tid * 4;
    float4 xv = *(const float4*)&X[(size_t)bq * Dn + j];
    float4 yv = *(const float4*)&Y[(size_t)bq * Dn + j];
    xv.x += yv.x; xv.y += yv.y; xv.z += yv.z; xv.w += yv.w;
    float lsum = xv.x + xv.y + xv.z + xv.w;
    float lsq = xv.x * xv.x + xv.y * xv.y + xv.z * xv.z + xv.w * xv.w;
    float mean, rstd;
    block_ln_stats(lsum, lsq, red, mean, rstd);
    float4 g = *(const float4*)&g2[j];
    float4 be = *(const float4*)&b2[j];
    float4 o;
    o.x = (xv.x - mean) * rstd * g.x + be.x;
    o.y = (xv.y - mean) * rstd * g.y + be.y;
    o.z = (xv.z - mean) * rstd * g.z + be.z;
    o.w = (xv.w - mean) * rstd * g.w + be.w;
    *(float4*)&out[(size_t)bq * Dn + j] = o;
}

extern "C" void kernel_launch(void* const* d_in, const int* in_sizes, int n_in,
                              void* d_out, int out_size, void* d_ws, size_t ws_size,
                              hipStream_t stream) {
    const float* key_in   = (const float*)d_in[0];
    const float* query_in = (const float*)d_in[1];
    const float* value_in = (const float*)d_in[2];
    const float* residual = (const float*)d_in[3];
    const float* Wk  = (const float*)d_in[4];
    const float* Wq  = (const float*)d_in[5];
    const float* Wv  = (const float*)d_in[6];
    const float* Wf  = (const float*)d_in[7];
    const float* bf  = (const float*)d_in[8];
    const float* g1  = (const float*)d_in[9];
    const float* b1  = (const float*)d_in[10];
    const float* Wm1 = (const float*)d_in[11];
    const float* bm1 = (const float*)d_in[12];
    const float* Wm2 = (const float*)d_in[13];
    const float* bm2 = (const float*)d_in[14];
    const float* Wm3 = (const float*)d_in[15];
    const float* bm3 = (const float*)d_in[16];
    const float* g2  = (const float*)d_in[17];
    const float* b2  = (const float*)d_in[18];
    float* ws  = (float*)d_ws;
    float* out = (float*)d_out;

    // zero P accumulators (ws is poisoned 0xAA before every launch)
    hipMemsetAsync(ws + OFF_PC, 0, 2 * 65536 * sizeof(float), stream);

    k_trig<<<512, 256, 0, stream>>>(key_in, query_in, Wk, Wq, ws);
    k_phase<<<dim3(8, 4, 8), 256, 0, stream>>>(value_in, ws + OFF_CK, ws + OFF_SK,
                                               ws + OFF_PC, ws + OFF_PS);
    k_cv<<<64, 128, 0, stream>>>(ws + OFF_PC, ws + OFF_PS, Wv, ws + OFF_CV, ws + OFF_SV);
    k_m<<<64, 256, 0, stream>>>(ws + OFF_CV, ws + OFF_SV, Wf, ws + OFF_M);
    k_denom<<<dim3(8, 32), 256, 0, stream>>>(ws, ws + OFF_DEN);
    k_x<<<8192, 256, 0, stream>>>(residual, bf, g1, b1, ws, ws + OFF_X);

    // MLP: h1 -> ws, h2 -> d_out (scratch), y -> ws (reuse h1), final -> d_out
    sgemm<<<dim3(64, 8), 256, 0, stream>>>(ws + OFF_X, Wm1, bm1, ws + OFF_H1, 1);
    sgemm<<<dim3(64, 8), 256, 0, stream>>>(ws + OFF_H1, Wm2, bm2, out, 1);
    sgemm<<<dim3(64, 8), 256, 0, stream>>>(out, Wm3, bm3, ws + OFF_H1, 0);
    k_final<<<8192, 256, 0, stream>>>(ws + OFF_X, ws + OFF_H1, g2, b2, out);
}

// Round 3
// 506.617 us; speedup vs baseline: 1.9531x; 1.9531x over previous
//
#include <hip/hip_runtime.h>
#include <math.h>

#define B_ 8
#define SQn 1024
#define SKn 1024
#define Dn 1024
#define Hn 8
#define DHn 128

// workspace float offsets
#define OFF_CQ 0
#define OFF_SQ 65536
#define OFF_CK 131072
#define OFF_SK 196608
#define OFF_PC 262144
#define OFF_PS 327680
#define OFF_CV 393216
#define OFF_SV 401408
#define OFF_M  409600
#define OFF_DEN 540672
#define OFF_X  606208      // Xpair: 8192 x 2048 bf16 = 8M float slots
#define OFF_H1 8994816     // H1pair (bf16) then y (fp32): 8M float slots
#define OFF_WT 17383424    // 3 weight pairs, each 1024x2048 bf16 = 1M float slots
// total: 20530176 floats = 78.3 MiB

typedef __attribute__((ext_vector_type(8))) short short8;
typedef __attribute__((ext_vector_type(4))) float f32x4;

__device__ __forceinline__ unsigned short f2bf(float f) {
    unsigned int u = __float_as_uint(f);
    unsigned int r = (u + 0x7fffu + ((u >> 16) & 1u)) >> 16;
    return (unsigned short)r;
}
__device__ __forceinline__ float bf2f(unsigned short h) {
    return __uint_as_float(((unsigned int)h) << 16);
}

__device__ __forceinline__ void gld16(const unsigned short* g, unsigned short* l) {
    __builtin_amdgcn_global_load_lds(
        (const __attribute__((address_space(1))) void*)g,
        (__attribute__((address_space(3))) void*)l, 16, 0, 0);
}

// ---------------- prep: per-head scalar q/k trig ----------------
__global__ void k_trig(const float* __restrict__ key_in, const float* __restrict__ query_in,
                       const float* __restrict__ Wk, const float* __restrict__ Wq,
                       float* __restrict__ ws) {
    int idx = blockIdx.x * blockDim.x + threadIdx.x;   // 131072 threads
    const int n = B_ * SQn * Hn;                       // 65536
    if (idx < n) {
        int h = idx & 7, bs = idx >> 3;
        float v = query_in[bs] * Wq[h];
        ws[OFF_CQ + idx] = cosf(v);
        ws[OFF_SQ + idx] = sinf(v);
    } else {
        int i2 = idx - n;
        int h = i2 & 7, bs = i2 >> 3;
        float v = key_in[bs] * Wk[h];
        ws[OFF_CK + i2] = cosf(v);
        ws[OFF_SK + i2] = sinf(v);
    }
}

// ---------------- weight transpose + bf16 hi/lo split ----------------
// in: W fp32 [1024 k][1024 n]; out: WT pair [n][2048]: cols 0..1023 = hi(W^T), 1024..2047 = lo
__global__ void k_wsplit(const float* __restrict__ W0, const float* __restrict__ W1,
                         const float* __restrict__ W2, unsigned short* __restrict__ wt) {
    __shared__ float tile[64][65];
    const float* W = (blockIdx.z == 0) ? W0 : (blockIdx.z == 1) ? W1 : W2;
    unsigned short* out = wt + (size_t)blockIdx.z * 2097152;
    const int k0 = blockIdx.x * 64, n0 = blockIdx.y * 64;
    const int tx = threadIdx.x & 63, ty = threadIdx.x >> 6;  // 64 x 4
    #pragma unroll
    for (int i = 0; i < 16; ++i) {
        int r = ty + i * 4;
        tile[r][tx] = W[(size_t)(k0 + r) * Dn + n0 + tx];
    }
    __syncthreads();
    #pragma unroll
    for (int i = 0; i < 16; ++i) {
        int r = ty + i * 4;                 // n - n0
        float v = tile[tx][r];              // W[k0+tx][n0+r] = W^T[n0+r][k0+tx]
        unsigned short hi = f2bf(v);
        unsigned short lo = f2bf(v - bf2f(hi));
        out[(size_t)(n0 + r) * 2048 + k0 + tx] = hi;
        out[(size_t)(n0 + r) * 2048 + 1024 + k0 + tx] = lo;
    }
}

// ---------------- P[b,h,i] = sum_k trig(k)*value_in[b,k,i] ----------------
__global__ void k_phase(const float* __restrict__ value_in, const float* __restrict__ ck,
                        const float* __restrict__ sk, float* __restrict__ Pc,
                        float* __restrict__ Ps) {
    __shared__ __align__(16) float ckk[1024];
    __shared__ __align__(16) float skk[1024];
    const int b = blockIdx.x, it = blockIdx.y, kc = blockIdx.z;
    const int tid = threadIdx.x;
    const int base = (b * SKn + kc * 128) * Hn;
    *(float4*)&ckk[tid * 4] = *(const float4*)&ck[base + tid * 4];
    *(float4*)&skk[tid * 4] = *(const float4*)&sk[base + tid * 4];
    __syncthreads();
    const int i = it * 256 + tid;
    float aC[8] = {0,0,0,0,0,0,0,0}, aS[8] = {0,0,0,0,0,0,0,0};
    const float* vp = value_in + (size_t)(b * SKn + kc * 128) * Dn + i;
    for (int kk = 0; kk < 128; ++kk) {
        float v = vp[(size_t)kk * Dn];
        float4 c0 = *(const float4*)&ckk[kk * 8];
        float4 c1 = *(const float4*)&ckk[kk * 8 + 4];
        float4 s0 = *(const float4*)&skk[kk * 8];
        float4 s1 = *(const float4*)&skk[kk * 8 + 4];
        aC[0] = fmaf(v, c0.x, aC[0]); aC[1] = fmaf(v, c0.y, aC[1]);
        aC[2] = fmaf(v, c0.z, aC[2]); aC[3] = fmaf(v, c0.w, aC[3]);
        aC[4] = fmaf(v, c1.x, aC[4]); aC[5] = fmaf(v, c1.y, aC[5]);
        aC[6] = fmaf(v, c1.z, aC[6]); aC[7] = fmaf(v, c1.w, aC[7]);
        aS[0] = fmaf(v, s0.x, aS[0]); aS[1] = fmaf(v, s0.y, aS[1]);
        aS[2] = fmaf(v, s0.z, aS[2]); aS[3] = fmaf(v, s0.w, aS[3]);
        aS[4] = fmaf(v, s1.x, aS[4]); aS[5] = fmaf(v, s1.y, aS[5]);
        aS[6] = fmaf(v, s1.z, aS[6]); aS[7] = fmaf(v, s1.w, aS[7]);
    }
    #pragma unroll
    for (int h = 0; h < 8; ++h) {
        atomicAdd(&Pc[(b * Hn + h) * Dn + i], aC[h]);
        atomicAdd(&Ps[(b * Hn + h) * Dn + i], aS[h]);
    }
}

// ---------------- Cv/Sv[b,h,d] = sum_i P[b,h,i]*Wv[i, h*128+d] ----------------
__global__ void k_cv(const float* __restrict__ Pc, const float* __restrict__ Ps,
                     const float* __restrict__ Wv, float* __restrict__ Cv,
                     float* __restrict__ Sv) {
    const int bh = blockIdx.x;
    const int ic = blockIdx.y;     // 8 chunks of 128 i's
    const int h = bh & 7;
    const int d = threadIdx.x;     // 128
    float ac = 0.f, as = 0.f;
    const float* wp = Wv + (size_t)(ic * 128) * Dn + h * DHn + d;
    const float* pc = Pc + bh * Dn + ic * 128;
    const float* ps = Ps + bh * Dn + ic * 128;
    #pragma unroll 4
    for (int i = 0; i < 128; ++i) {
        float w = wp[(size_t)i * Dn];
        ac = fmaf(pc[i], w, ac);
        as = fmaf(ps[i], w, as);
    }
    atomicAdd(&Cv[bh * DHn + d], ac);
    atomicAdd(&Sv[bh * DHn + d], as);
}

// ---------------- M[b,t,j]: t=h -> Cv@Wf slice, t=8+h -> Sv@Wf slice ----------------
__global__ void k_m(const float* __restrict__ Cv, const float* __restrict__ Sv,
                    const float* __restrict__ Wf, float* __restrict__ M) {
    const int bh = blockIdx.x;
    const int dc = blockIdx.y;     // 4 chunks of 32 d's
    const int b = bh >> 3, h = bh & 7;
    const int j = threadIdx.x * 4;
    float4 ac = {0,0,0,0}, as = {0,0,0,0};
    #pragma unroll 4
    for (int dd = 0; dd < 32; ++dd) {
        int d = dc * 32 + dd;
        float cv = Cv[bh * DHn + d];
        float sv = Sv[bh * DHn + d];
        float4 w = *(const float4*)&Wf[(size_t)(h * DHn + d) * Dn + j];
        ac.x = fmaf(cv, w.x, ac.x); ac.y = fmaf(cv, w.y, ac.y);
        ac.z = fmaf(cv, w.z, ac.z); ac.w = fmaf(cv, w.w, ac.w);
        as.x = fmaf(sv, w.x, as.x); as.y = fmaf(sv, w.y, as.y);
        as.z = fmaf(sv, w.z, as.z); as.w = fmaf(sv, w.w, as.w);
    }
    float* mc = &M[(size_t)(b * 16 + h) * Dn + j];
    float* ms = &M[(size_t)(b * 16 + 8 + h) * Dn + j];
    atomicAdd(mc + 0, ac.x); atomicAdd(mc + 1, ac.y);
    atomicAdd(mc + 2, ac.z); atomicAdd(mc + 3, ac.w);
    atomicAdd(ms + 0, as.x); atomicAdd(ms + 1, as.y);
    atomicAdd(ms + 2, as.z); atomicAdd(ms + 3, as.w);
}

// ---------------- denom[b,q,h] = sum_k |cq*ck + sq*sk| + eps ----------------
__global__ void k_denom(const float* __restrict__ ws, float* __restrict__ den) {
    __shared__ __align__(16) float ckk[8][132];
    __shared__ __align__(16) float skk[8][132];
    const int b = blockIdx.x, qt = blockIdx.y;
    const int tid = threadIdx.x;
    const int qq = tid >> 3, h = tid & 7;
    const int q = qt * 32 + qq;
    const float cqv = ws[OFF_CQ + (b * SQn + q) * Hn + h];
    const float sqv = ws[OFF_SQ + (b * SQn + q) * Hn + h];
    float acc = 0.f;
    for (int kc = 0; kc < 8; ++kc) {
        __syncthreads();
        const int base = (b * SKn + kc * 128) * Hn;
        float4 c4 = *(const float4*)&ws[OFF_CK + base + tid * 4];
        float4 s4 = *(const float4*)&ws[OFF_SK + base + tid * 4];
        #pragma unroll
        for (int u = 0; u < 4; ++u) {
            int f = tid * 4 + u;
            ckk[f & 7][f >> 3] = ((const float*)&c4)[u];
            skk[f & 7][f >> 3] = ((const float*)&s4)[u];
        }
        __syncthreads();
        #pragma unroll
        for (int kv = 0; kv < 32; ++kv) {
            float4 c = *(const float4*)&ckk[h][kv * 4];
            float4 s = *(const float4*)&skk[h][kv * 4];
            acc += fabsf(cqv * c.x + sqv * s.x);
            acc += fabsf(cqv * c.y + sqv * s.y);
            acc += fabsf(cqv * c.z + sqv * s.z);
            acc += fabsf(cqv * c.w + sqv * s.w);
        }
    }
    den[(b * SQn + q) * Hn + h] = acc + 1e-6f;
}

// ---------------- block LayerNorm stats helper ----------------
__device__ inline void block_ln_stats(float lsum, float lsq, float* red,
                                      float& mean, float& rstd) {
    #pragma unroll
    for (int off = 32; off; off >>= 1) {
        lsum += __shfl_xor(lsum, off);
        lsq  += __shfl_xor(lsq, off);
    }
    const int wid = threadIdx.x >> 6;
    if ((threadIdx.x & 63) == 0) { red[wid * 2] = lsum; red[wid * 2 + 1] = lsq; }
    __syncthreads();
    if (threadIdx.x == 0) {
        float s  = red[0] + red[2] + red[4] + red[6];
        float ss = red[1] + red[3] + red[5] + red[7];
        float m = s * (1.0f / Dn);
        red[8] = m;
        red[9] = rsqrtf(ss * (1.0f / Dn) - m * m + 1e-5f);
    }
    __syncthreads();
    mean = red[8];
    rstd = red[9];
}

// ---------------- x = LN(residual + rank16-combine + bf) -> bf16 hi/lo pair ----------------
__global__ void k_x(const float* __restrict__ residual, const float* __restrict__ bf,
                    const float* __restrict__ g1, const float* __restrict__ b1,
                    const float* __restrict__ ws, unsigned short* __restrict__ Xp) {
    __shared__ float lcoef[16];
    __shared__ float red[12];
    const int bq = blockIdx.x;       // b*SQ + q
    const int b = bq >> 10;
    const int tid = threadIdx.x;
    if (tid < 8) {
        float dinv = 1.0f / ws[OFF_DEN + bq * Hn + tid];
        lcoef[tid]     = ws[OFF_CQ + bq * Hn + tid] * dinv;
        lcoef[8 + tid] = ws[OFF_SQ + bq * Hn + tid] * dinv;
    }
    __syncthreads();
    const int j = tid * 4;
    float4 acc = *(const float4*)&bf[j];
    const float* Mp = ws + OFF_M + (size_t)b * 16 * Dn + j;
    #pragma unroll
    for (int t = 0; t < 16; ++t) {
        float cf = lcoef[t];
        float4 m4 = *(const float4*)&Mp[(size_t)t * Dn];
        acc.x = fmaf(cf, m4.x, acc.x); acc.y = fmaf(cf, m4.y, acc.y);
        acc.z = fmaf(cf, m4.z, acc.z); acc.w = fmaf(cf, m4.w, acc.w);
    }
    float4 r = *(const float4*)&residual[(size_t)bq * Dn + j];
    acc.x += r.x; acc.y += r.y; acc.z += r.z; acc.w += r.w;
    float lsum = acc.x + acc.y + acc.z + acc.w;
    float lsq = acc.x * acc.x + acc.y * acc.y + acc.z * acc.z + acc.w * acc.w;
    float mean, rstd;
    block_ln_stats(lsum, lsq, red, mean, rstd);
    float4 g = *(const float4*)&g1[j];
    float4 be = *(const float4*)&b1[j];
    float o[4];
    o[0] = (acc.x - mean) * rstd * g.x + be.x;
    o[1] = (acc.y - mean) * rstd * g.y + be.y;
    o[2] = (acc.z - mean) * rstd * g.z + be.z;
    o[3] = (acc.w - mean) * rstd * g.w + be.w;
    ushort4 hi, lo;
    unsigned short* hp = (unsigned short*)&hi;
    unsigned short* lp = (unsigned short*)&lo;
    #pragma unroll
    for (int u = 0; u < 4; ++u) {
        hp[u] = f2bf(o[u]);
        lp[u] = f2bf(o[u] - bf2f(hp[u]));
    }
    *(ushort4*)&Xp[(size_t)bq * 2048 + j] = hi;
    *(ushort4*)&Xp[(size_t)bq * 2048 + 1024 + j] = lo;
}

// ---------------- bf16 split MFMA GEMM ----------------
// C[8192,1024] = act( (Ah+Al)[8192,1024] @ (Wh+Wl)[1024,1024] + bias )
// A pair layout [m][2048]: 0..1023 hi, 1024..2047 lo. W pair: [n][2048] transposed.
// 3 phases: Ah*Wh, Al*Wh, Ah*Wl accumulated in fp32.
// mode 0: write bf16 pair + relu to Cp ; mode 1: write fp32 (no relu) to Cf
__global__ __launch_bounds__(256) void gemm_split(const unsigned short* __restrict__ Ap,
                                                  const unsigned short* __restrict__ Wp,
                                                  const float* __restrict__ bias,
                                                  unsigned short* __restrict__ Cp,
                                                  float* __restrict__ Cf, int mode) {
    __shared__ __align__(16) unsigned short As[128 * 64];
    __shared__ __align__(16) unsigned short Bs[128 * 64];
    const int t = threadIdx.x;
    // XCD-aware swizzle over 512 blocks: each XCD gets one n-panel
    const int orig = blockIdx.x;
    const int swz = (orig & 7) * 64 + (orig >> 3);
    const int m0 = (swz & 63) * 128;
    const int n0 = (swz >> 6) * 128;

    const int w = t >> 6;          // wave 0..3
    const int wm = (w >> 1) * 64;  // wave row offset
    const int wn = (w & 1) * 64;   // wave col offset
    const int l15 = t & 15;
    const int kq = (t >> 4) & 3;   // lane k-quad

    const int tr = t >> 3;         // staging row 0..31
    const int tc = (t & 7) * 8;    // staging col (elements)

    f32x4 acc[4][4];
    #pragma unroll
    for (int m = 0; m < 4; ++m)
        #pragma unroll
        for (int n = 0; n < 4; ++n)
            acc[m][n] = (f32x4){0.f, 0.f, 0.f, 0.f};

    for (int ph = 0; ph < 3; ++ph) {
        const unsigned short* Aph = Ap + ((ph == 1) ? 1024 : 0);
        const unsigned short* Bph = Wp + ((ph == 2) ? 1024 : 0);
        for (int kt = 0; kt < 16; ++kt) {
            const int k0 = kt * 64;
            #pragma unroll
            for (int i = 0; i < 4; ++i)
                gld16(Aph + (size_t)(m0 + i * 32 + tr) * 2048 + k0 + tc,
                      &As[(i * 32 + tr) * 64 + tc]);
            #pragma unroll
            for (int i = 0; i < 4; ++i)
                gld16(Bph + (size_t)(n0 + i * 32 + tr) * 2048 + k0 + tc,
                      &Bs[(i * 32 + tr) * 64 + tc]);
            __syncthreads();   // drain loads (vmcnt0) + join
            #pragma unroll
            for (int ks = 0; ks < 2; ++ks) {
                short8 af[4], bfv[4];
                #pragma unroll
                for (int m = 0; m < 4; ++m)
                    af[m] = *(const short8*)&As[(wm + m * 16 + l15) * 64 + ks * 32 + kq * 8];
                #pragma unroll
                for (int n = 0; n < 4; ++n)
                    bfv[n] = *(const short8*)&Bs[(wn + n * 16 + l15) * 64 + ks * 32 + kq * 8];
                #pragma unroll
                for (int m = 0; m < 4; ++m)
                    #pragma unroll
                    for (int n = 0; n < 4; ++n)
                        acc[m][n] = __builtin_amdgcn_mfma_f32_16x16x32_bf16(
                            af[m], bfv[n], acc[m][n], 0, 0, 0);
            }
            __syncthreads();   // all waves done reading before next overwrite
        }
    }

    // epilogue
    #pragma unroll
    for (int n = 0; n < 4; ++n) {
        const int col = n0 + wn + n * 16 + l15;
        const float bv = bias[col];
        #pragma unroll
        for (int m = 0; m < 4; ++m) {
            #pragma unroll
            for (int r = 0; r < 4; ++r) {
                const int row = m0 + wm + m * 16 + kq * 4 + r;
                float c = acc[m][n][r] + bv;
                if (mode == 0) {
                    c = fmaxf(c, 0.f);
                    unsigned short hi = f2bf(c);
                    unsigned short lo = f2bf(c - bf2f(hi));
                    Cp[(size_t)row * 2048 + col] = hi;
                    Cp[(size_t)row * 2048 + 1024 + col] = lo;
                } else {
                    Cf[(size_t)row * 1024 + col] = c;
                }
            }
        }
    }
}

// ---------------- out = LN(x + mlp_out, g2, b2) ----------------
__global__ void k_final(const unsigned short* __restrict__ Xp, const float* __restrict__ Y,
                        const float* __restrict__ g2, const float* __restrict__ b2,
                        float* __restrict__ out) {
    __shared__ float red[12];
    const int bq = blockIdx.x;
    const int tid = threadIdx.x;
    const int j = tid * 4;
    ushort4 xh = *(const ushort4*)&Xp[(size_t)bq * 2048 + j];
    ushort4 xl = *(const ushort4*)&Xp[(size_t)bq * 2048 + 1024 + j];
    float4 yv = *(const float4*)&Y[(size_t)bq * Dn + j];
    float xv[4];
    xv[0] = bf2f(xh.x) + bf2f(xl.x) + yv.x;
    xv[1] = bf2f(xh.y) + bf2f(xl.y) + yv.y;
    xv[2] = bf2f(xh.z) + bf2f(xl.z) + yv.z;
    xv[3] = bf2f(xh.w) + bf2f(xl.w) + yv.w;
    float lsum = xv[0] + xv[1] + xv[2] + xv[3];
    float lsq = xv[0]*xv[0] + xv[1]*xv[1] + xv[2]*xv[2] + xv[3]*xv[3];
    float mean, rstd;
    block_ln_stats(lsum, lsq, red, mean, rstd);
    float4 g = *(const float4*)&g2[j];
    float4 be = *(const float4*)&b2[j];
    float4 o;
    o.x = (xv[0] - mean) * rstd * g.x + be.x;
    o.y = (xv[1] - mean) * rstd * g.y + be.y;
    o.z = (xv[2] - mean) * rstd * g.z + be.z;
    o.w = (xv[3] - mean) * rstd * g.w + be.w;
    *(float4*)&out[(size_t)bq * Dn + j] = o;
}

extern "C" void kernel_launch(void* const* d_in, const int* in_sizes, int n_in,
                              void* d_out, int out_size, void* d_ws, size_t ws_size,
                              hipStream_t stream) {
    const float* key_in   = (const float*)d_in[0];
    const float* query_in = (const float*)d_in[1];
    const float* value_in = (const float*)d_in[2];
    const float* residual = (const float*)d_in[3];
    const float* Wk  = (const float*)d_in[4];
    const float* Wq  = (const float*)d_in[5];
    const float* Wv  = (const float*)d_in[6];
    const float* Wf  = (const float*)d_in[7];
    const float* bf  = (const float*)d_in[8];
    const float* g1  = (const float*)d_in[9];
    const float* b1  = (const float*)d_in[10];
    const float* Wm1 = (const float*)d_in[11];
    const float* bm1 = (const float*)d_in[12];
    const float* Wm2 = (const float*)d_in[13];
    const float* bm2 = (const float*)d_in[14];
    const float* Wm3 = (const float*)d_in[15];
    const float* bm3 = (const float*)d_in[16];
    const float* g2  = (const float*)d_in[17];
    const float* b2  = (const float*)d_in[18];
    float* ws  = (float*)d_ws;
    float* out = (float*)d_out;

    unsigned short* Xp  = (unsigned short*)(ws + OFF_X);
    unsigned short* H1p = (unsigned short*)(ws + OFF_H1);   // layer-1 output pair
    unsigned short* H2p = (unsigned short*)out;             // layer-2 output pair (d_out scratch)
    float*          Yf  = ws + OFF_H1;                      // layer-3 fp32 output (over H1p, dead)
    unsigned short* WT  = (unsigned short*)(ws + OFF_WT);

    // zero P/Cv/Sv/M accumulators (ws is poisoned 0xAA before every launch)
    hipMemsetAsync(ws + OFF_PC, 0, (size_t)(OFF_DEN - OFF_PC) * sizeof(float), stream);

    k_trig<<<512, 256, 0, stream>>>(key_in, query_in, Wk, Wq, ws);
    k_wsplit<<<dim3(16, 16, 3), 256, 0, stream>>>(Wm1, Wm2, Wm3, WT);
    k_phase<<<dim3(8, 4, 8), 256, 0, stream>>>(value_in, ws + OFF_CK, ws + OFF_SK,
                                               ws + OFF_PC, ws + OFF_PS);
    k_cv<<<dim3(64, 8), 128, 0, stream>>>(ws + OFF_PC, ws + OFF_PS, Wv,
                                          ws + OFF_CV, ws + OFF_SV);
    k_m<<<dim3(64, 4), 256, 0, stream>>>(ws + OFF_CV, ws + OFF_SV, Wf, ws + OFF_M);
    k_denom<<<dim3(8, 32), 256, 0, stream>>>(ws, ws + OFF_DEN);
    k_x<<<8192, 256, 0, stream>>>(residual, bf, g1, b1, ws, Xp);

    // MLP via split-bf16 MFMA GEMMs
    gemm_split<<<512, 256, 0, stream>>>(Xp, WT, bm1, H1p, nullptr, 0);
    gemm_split<<<512, 256, 0, stream>>>(H1p, WT + 2097152, bm2, H2p, nullptr, 0);
    gemm_split<<<512, 256, 0, stream>>>(H2p, WT + 2 * 2097152, bm3, nullptr, Yf, 1);
    k_final<<<8192, 256, 0, stream>>>(Xp, Yf, g2, b2, out);
}

// Round 5
// 411.672 us; speedup vs baseline: 2.4035x; 1.2306x over previous
//
#include <hip/hip_runtime.h>
#include <math.h>

#define B_ 8
#define SQn 1024
#define SKn 1024
#define Dn 1024
#define Hn 8
#define DHn 128

// workspace float offsets
#define OFF_CQ 0
#define OFF_SQ 65536
#define OFF_CK 131072
#define OFF_SK 196608
#define OFF_PC 262144
#define OFF_PS 327680
#define OFF_CV 393216
#define OFF_SV 401408
#define OFF_M  409600
#define OFF_DEN 540672
#define OFF_X  606208      // Xpair: 8192 x 2048 bf16 = 8M float slots
#define OFF_H1 8994816     // H1pair (bf16) then y (fp32): 8M float slots
#define OFF_WT 17383424    // 3 weight pairs, each 1024x2048 bf16 = 1M float slots
// total: 20530176 floats = 78.3 MiB

typedef __attribute__((ext_vector_type(8))) short short8;
typedef __attribute__((ext_vector_type(4))) float f32x4;

__device__ __forceinline__ unsigned short f2bf(float f) {
    unsigned int u = __float_as_uint(f);
    unsigned int r = (u + 0x7fffu + ((u >> 16) & 1u)) >> 16;
    return (unsigned short)r;
}
__device__ __forceinline__ float bf2f(unsigned short h) {
    return __uint_as_float(((unsigned int)h) << 16);
}

__device__ __forceinline__ void gld16(const unsigned short* g, unsigned short* l) {
    __builtin_amdgcn_global_load_lds(
        (const __attribute__((address_space(1))) void*)g,
        (__attribute__((address_space(3))) void*)l, 16, 0, 0);
}

// ---------------- prep: per-head scalar q/k trig ----------------
__global__ void k_trig(const float* __restrict__ key_in, const float* __restrict__ query_in,
                       const float* __restrict__ Wk, const float* __restrict__ Wq,
                       float* __restrict__ ws) {
    int idx = blockIdx.x * blockDim.x + threadIdx.x;   // 131072 threads
    const int n = B_ * SQn * Hn;                       // 65536
    if (idx < n) {
        int h = idx & 7, bs = idx >> 3;
        float v = query_in[bs] * Wq[h];
        ws[OFF_CQ + idx] = cosf(v);
        ws[OFF_SQ + idx] = sinf(v);
    } else {
        int i2 = idx - n;
        int h = i2 & 7, bs = i2 >> 3;
        float v = key_in[bs] * Wk[h];
        ws[OFF_CK + i2] = cosf(v);
        ws[OFF_SK + i2] = sinf(v);
    }
}

// ---------------- weight transpose + bf16 hi/lo split ----------------
__global__ void k_wsplit(const float* __restrict__ W0, const float* __restrict__ W1,
                         const float* __restrict__ W2, unsigned short* __restrict__ wt) {
    __shared__ float tile[64][65];
    const float* W = (blockIdx.z == 0) ? W0 : (blockIdx.z == 1) ? W1 : W2;
    unsigned short* out = wt + (size_t)blockIdx.z * 2097152;
    const int k0 = blockIdx.x * 64, n0 = blockIdx.y * 64;
    const int tx = threadIdx.x & 63, ty = threadIdx.x >> 6;  // 64 x 4
    #pragma unroll
    for (int i = 0; i < 16; ++i) {
        int r = ty + i * 4;
        tile[r][tx] = W[(size_t)(k0 + r) * Dn + n0 + tx];
    }
    __syncthreads();
    #pragma unroll
    for (int i = 0; i < 16; ++i) {
        int r = ty + i * 4;                 // n - n0
        float v = tile[tx][r];              // W^T[n0+r][k0+tx]
        unsigned short hi = f2bf(v);
        unsigned short lo = f2bf(v - bf2f(hi));
        out[(size_t)(n0 + r) * 2048 + k0 + tx] = hi;
        out[(size_t)(n0 + r) * 2048 + 1024 + k0 + tx] = lo;
    }
}

// ---------------- P[b,h,i] = sum_k trig(k)*value_in[b,k,i] ----------------
// grid (8, 4, 16): b, i-chunk(256), k-chunk(64)
__global__ void k_phase(const float* __restrict__ value_in, const float* __restrict__ ck,
                        const float* __restrict__ sk, float* __restrict__ Pc,
                        float* __restrict__ Ps) {
    __shared__ __align__(16) float ckk[512];
    __shared__ __align__(16) float skk[512];
    const int b = blockIdx.x, it = blockIdx.y, kc = blockIdx.z;
    const int tid = threadIdx.x;
    const int base = (b * SKn + kc * 64) * Hn;
    *(float2*)&ckk[tid * 2] = *(const float2*)&ck[base + tid * 2];
    *(float2*)&skk[tid * 2] = *(const float2*)&sk[base + tid * 2];
    __syncthreads();
    const int i = it * 256 + tid;
    float aC[8] = {0,0,0,0,0,0,0,0}, aS[8] = {0,0,0,0,0,0,0,0};
    const float* vp = value_in + (size_t)(b * SKn + kc * 64) * Dn + i;
    #pragma unroll 4
    for (int kk = 0; kk < 64; ++kk) {
        float v = vp[(size_t)kk * Dn];
        float4 c0 = *(const float4*)&ckk[kk * 8];
        float4 c1 = *(const float4*)&ckk[kk * 8 + 4];
        float4 s0 = *(const float4*)&skk[kk * 8];
        float4 s1 = *(const float4*)&skk[kk * 8 + 4];
        aC[0] = fmaf(v, c0.x, aC[0]); aC[1] = fmaf(v, c0.y, aC[1]);
        aC[2] = fmaf(v, c0.z, aC[2]); aC[3] = fmaf(v, c0.w, aC[3]);
        aC[4] = fmaf(v, c1.x, aC[4]); aC[5] = fmaf(v, c1.y, aC[5]);
        aC[6] = fmaf(v, c1.z, aC[6]); aC[7] = fmaf(v, c1.w, aC[7]);
        aS[0] = fmaf(v, s0.x, aS[0]); aS[1] = fmaf(v, s0.y, aS[1]);
        aS[2] = fmaf(v, s0.z, aS[2]); aS[3] = fmaf(v, s0.w, aS[3]);
        aS[4] = fmaf(v, s1.x, aS[4]); aS[5] = fmaf(v, s1.y, aS[5]);
        aS[6] = fmaf(v, s1.z, aS[6]); aS[7] = fmaf(v, s1.w, aS[7]);
    }
    #pragma unroll
    for (int h = 0; h < 8; ++h) {
        atomicAdd(&Pc[(b * Hn + h) * Dn + i], aC[h]);
        atomicAdd(&Ps[(b * Hn + h) * Dn + i], aS[h]);
    }
}

// ---------------- Cv/Sv[b,h,d] = sum_i P[b,h,i]*Wv[i, h*128+d] ----------------
// grid (64, 16): bh, i-chunk(64)
__global__ void k_cv(const float* __restrict__ Pc, const float* __restrict__ Ps,
                     const float* __restrict__ Wv, float* __restrict__ Cv,
                     float* __restrict__ Sv) {
    const int bh = blockIdx.x;
    const int ic = blockIdx.y;
    const int h = bh & 7;
    const int d = threadIdx.x;     // 128
    float ac = 0.f, as = 0.f;
    const float* wp = Wv + (size_t)(ic * 64) * Dn + h * DHn + d;
    const float* pc = Pc + bh * Dn + ic * 64;
    const float* ps = Ps + bh * Dn + ic * 64;
    #pragma unroll 4
    for (int i = 0; i < 64; ++i) {
        float w = wp[(size_t)i * Dn];
        ac = fmaf(pc[i], w, ac);
        as = fmaf(ps[i], w, as);
    }
    atomicAdd(&Cv[bh * DHn + d], ac);
    atomicAdd(&Sv[bh * DHn + d], as);
}

// ---------------- M[b,t,j]: t=h -> Cv@Wf slice, t=8+h -> Sv@Wf slice ----------------
__global__ void k_m(const float* __restrict__ Cv, const float* __restrict__ Sv,
                    const float* __restrict__ Wf, float* __restrict__ M) {
    const int bh = blockIdx.x;
    const int dc = blockIdx.y;     // 4 chunks of 32 d's
    const int b = bh >> 3, h = bh & 7;
    const int j = threadIdx.x * 4;
    float4 ac = {0,0,0,0}, as = {0,0,0,0};
    #pragma unroll 4
    for (int dd = 0; dd < 32; ++dd) {
        int d = dc * 32 + dd;
        float cv = Cv[bh * DHn + d];
        float sv = Sv[bh * DHn + d];
        float4 w = *(const float4*)&Wf[(size_t)(h * DHn + d) * Dn + j];
        ac.x = fmaf(cv, w.x, ac.x); ac.y = fmaf(cv, w.y, ac.y);
        ac.z = fmaf(cv, w.z, ac.z); ac.w = fmaf(cv, w.w, ac.w);
        as.x = fmaf(sv, w.x, as.x); as.y = fmaf(sv, w.y, as.y);
        as.z = fmaf(sv, w.z, as.z); as.w = fmaf(sv, w.w, as.w);
    }
    float* mc = &M[(size_t)(b * 16 + h) * Dn + j];
    float* ms = &M[(size_t)(b * 16 + 8 + h) * Dn + j];
    atomicAdd(mc + 0, ac.x); atomicAdd(mc + 1, ac.y);
    atomicAdd(mc + 2, ac.z); atomicAdd(mc + 3, ac.w);
    atomicAdd(ms + 0, as.x); atomicAdd(ms + 1, as.y);
    atomicAdd(ms + 2, as.z); atomicAdd(ms + 3, as.w);
}

// ---------------- denom partial: atomicAdd sum_k |cq*ck + sq*sk| ----------------
// grid (8, 32, 2): b, q-tile(32), kc-half (4 chunks of 128 keys each)
__global__ void k_denom(const float* __restrict__ ws, float* __restrict__ den) {
    __shared__ __align__(16) float ckk[8][132];
    __shared__ __align__(16) float skk[8][132];
    const int b = blockIdx.x, qt = blockIdx.y, zh = blockIdx.z;
    const int tid = threadIdx.x;
    const int qq = tid >> 3, h = tid & 7;
    const int q = qt * 32 + qq;
    const float cqv = ws[OFF_CQ + (b * SQn + q) * Hn + h];
    const float sqv = ws[OFF_SQ + (b * SQn + q) * Hn + h];
    float acc = 0.f;
    for (int kc = zh * 4; kc < zh * 4 + 4; ++kc) {
        __syncthreads();
        const int base = (b * SKn + kc * 128) * Hn;
        float4 c4 = *(const float4*)&ws[OFF_CK + base + tid * 4];
        float4 s4 = *(const float4*)&ws[OFF_SK + base + tid * 4];
        #pragma unroll
        for (int u = 0; u < 4; ++u) {
            int f = tid * 4 + u;
            ckk[f & 7][f >> 3] = ((const float*)&c4)[u];
            skk[f & 7][f >> 3] = ((const float*)&s4)[u];
        }
        __syncthreads();
        #pragma unroll
        for (int kv = 0; kv < 32; ++kv) {
            float4 c = *(const float4*)&ckk[h][kv * 4];
            float4 s = *(const float4*)&skk[h][kv * 4];
            acc += fabsf(cqv * c.x + sqv * s.x);
            acc += fabsf(cqv * c.y + sqv * s.y);
            acc += fabsf(cqv * c.z + sqv * s.z);
            acc += fabsf(cqv * c.w + sqv * s.w);
        }
    }
    atomicAdd(&den[(b * SQn + q) * Hn + h], acc);
}

// ---------------- block LayerNorm stats helper ----------------
__device__ inline void block_ln_stats(float lsum, float lsq, float* red,
                                      float& mean, float& rstd) {
    #pragma unroll
    for (int off = 32; off; off >>= 1) {
        lsum += __shfl_xor(lsum, off);
        lsq  += __shfl_xor(lsq, off);
    }
    const int wid = threadIdx.x >> 6;
    if ((threadIdx.x & 63) == 0) { red[wid * 2] = lsum; red[wid * 2 + 1] = lsq; }
    __syncthreads();
    if (threadIdx.x == 0) {
        float s  = red[0] + red[2] + red[4] + red[6];
        float ss = red[1] + red[3] + red[5] + red[7];
        float m = s * (1.0f / Dn);
        red[8] = m;
        red[9] = rsqrtf(ss * (1.0f / Dn) - m * m + 1e-5f);
    }
    __syncthreads();
    mean = red[8];
    rstd = red[9];
}

// ---------------- x = LN(residual + rank16-combine + bf) -> bf16 hi/lo pair ----------------
__global__ void k_x(const float* __restrict__ residual, const float* __restrict__ bf,
                    const float* __restrict__ g1, const float* __restrict__ b1,
                    const float* __restrict__ ws, unsigned short* __restrict__ Xp) {
    __shared__ float lcoef[16];
    __shared__ float red[12];
    const int bq = blockIdx.x;       // b*SQ + q
    const int b = bq >> 10;
    const int tid = threadIdx.x;
    if (tid < 8) {
        float dinv = 1.0f / (ws[OFF_DEN + bq * Hn + tid] + 1e-6f);
        lcoef[tid]     = ws[OFF_CQ + bq * Hn + tid] * dinv;
        lcoef[8 + tid] = ws[OFF_SQ + bq * Hn + tid] * dinv;
    }
    __syncthreads();
    const int j = tid * 4;
    float4 acc = *(const float4*)&bf[j];
    const float* Mp = ws + OFF_M + (size_t)b * 16 * Dn + j;
    #pragma unroll
    for (int t = 0; t < 16; ++t) {
        float cf = lcoef[t];
        float4 m4 = *(const float4*)&Mp[(size_t)t * Dn];
        acc.x = fmaf(cf, m4.x, acc.x); acc.y = fmaf(cf, m4.y, acc.y);
        acc.z = fmaf(cf, m4.z, acc.z); acc.w = fmaf(cf, m4.w, acc.w);
    }
    float4 r = *(const float4*)&residual[(size_t)bq * Dn + j];
    acc.x += r.x; acc.y += r.y; acc.z += r.z; acc.w += r.w;
    float lsum = acc.x + acc.y + acc.z + acc.w;
    float lsq = acc.x * acc.x + acc.y * acc.y + acc.z * acc.z + acc.w * acc.w;
    float mean, rstd;
    block_ln_stats(lsum, lsq, red, mean, rstd);
    float4 g = *(const float4*)&g1[j];
    float4 be = *(const float4*)&b1[j];
    float o[4];
    o[0] = (acc.x - mean) * rstd * g.x + be.x;
    o[1] = (acc.y - mean) * rstd * g.y + be.y;
    o[2] = (acc.z - mean) * rstd * g.z + be.z;
    o[3] = (acc.w - mean) * rstd * g.w + be.w;
    ushort4 hi, lo;
    unsigned short* hp = (unsigned short*)&hi;
    unsigned short* lp = (unsigned short*)&lo;
    #pragma unroll
    for (int u = 0; u < 4; ++u) {
        hp[u] = f2bf(o[u]);
        lp[u] = f2bf(o[u] - bf2f(hp[u]));
    }
    *(ushort4*)&Xp[(size_t)bq * 2048 + j] = hi;
    *(ushort4*)&Xp[(size_t)bq * 2048 + 1024 + j] = lo;
}

// ---------------- fused 3-term split-bf16 MFMA GEMM ----------------
// C = act( (Ah+Al) @ (Wh+Wl)^T + bias ), terms Ah*Wh + Al*Wh + Ah*Wl.
// Per k-tile: stage Ah,Al,Wh,Wl (64KB LDS) once, 96 MFMAs per barrier-pair.
__global__ __launch_bounds__(256) void gemm_split(const unsigned short* __restrict__ Ap,
                                                  const unsigned short* __restrict__ Wp,
                                                  const float* __restrict__ bias,
                                                  unsigned short* __restrict__ Cp,
                                                  float* __restrict__ Cf, int mode) {
    __shared__ __align__(16) unsigned short Ash[128 * 64];
    __shared__ __align__(16) unsigned short Asl[128 * 64];
    __shared__ __align__(16) unsigned short Bsh[128 * 64];
    __shared__ __align__(16) unsigned short Bsl[128 * 64];
    const int t = threadIdx.x;
    // XCD-aware swizzle over 512 blocks
    const int orig = blockIdx.x;
    const int swz = (orig & 7) * 64 + (orig >> 3);
    const int m0 = (swz & 63) * 128;
    const int n0 = (swz >> 6) * 128;

    const int w = t >> 6;          // wave 0..3
    const int wm = (w >> 1) * 64;
    const int wn = (w & 1) * 64;
    const int l15 = t & 15;
    const int kq = (t >> 4) & 3;

    const int tr = t >> 3;         // staging row 0..31
    const int tc = (t & 7) * 8;    // staging col (elements)

    f32x4 acc[4][4];
    #pragma unroll
    for (int m = 0; m < 4; ++m)
        #pragma unroll
        for (int n = 0; n < 4; ++n)
            acc[m][n] = (f32x4){0.f, 0.f, 0.f, 0.f};

    for (int kt = 0; kt < 16; ++kt) {
        const int k0 = kt * 64;
        #pragma unroll
        for (int i = 0; i < 4; ++i) {
            gld16(Ap + (size_t)(m0 + i * 32 + tr) * 2048 + k0 + tc,
                  &Ash[(i * 32 + tr) * 64 + tc]);
            gld16(Ap + (size_t)(m0 + i * 32 + tr) * 2048 + 1024 + k0 + tc,
                  &Asl[(i * 32 + tr) * 64 + tc]);
            gld16(Wp + (size_t)(n0 + i * 32 + tr) * 2048 + k0 + tc,
                  &Bsh[(i * 32 + tr) * 64 + tc]);
            gld16(Wp + (size_t)(n0 + i * 32 + tr) * 2048 + 1024 + k0 + tc,
                  &Bsl[(i * 32 + tr) * 64 + tc]);
        }
        __syncthreads();   // drain gld (vmcnt0) + join
        #pragma unroll
        for (int ks = 0; ks < 2; ++ks) {
            short8 afh[4], afl[4], bfh[4], bfl[4];
            #pragma unroll
            for (int m = 0; m < 4; ++m) {
                const int ro = (wm + m * 16 + l15) * 64 + ks * 32 + kq * 8;
                afh[m] = *(const short8*)&Ash[ro];
                afl[m] = *(const short8*)&Asl[ro];
            }
            #pragma unroll
            for (int n = 0; n < 4; ++n) {
                const int ro = (wn + n * 16 + l15) * 64 + ks * 32 + kq * 8;
                bfh[n] = *(const short8*)&Bsh[ro];
                bfl[n] = *(const short8*)&Bsl[ro];
            }
            #pragma unroll
            for (int m = 0; m < 4; ++m)
                #pragma unroll
                for (int n = 0; n < 4; ++n) {
                    acc[m][n] = __builtin_amdgcn_mfma_f32_16x16x32_bf16(
                        afh[m], bfh[n], acc[m][n], 0, 0, 0);
                    acc[m][n] = __builtin_amdgcn_mfma_f32_16x16x32_bf16(
                        afl[m], bfh[n], acc[m][n], 0, 0, 0);
                    acc[m][n] = __builtin_amdgcn_mfma_f32_16x16x32_bf16(
                        afh[m], bfl[n], acc[m][n], 0, 0, 0);
                }
        }
        __syncthreads();   // all waves done reading before next overwrite
    }

    // epilogue
    #pragma unroll
    for (int n = 0; n < 4; ++n) {
        const int col = n0 + wn + n * 16 + l15;
        const float bv = bias[col];
        #pragma unroll
        for (int m = 0; m < 4; ++m) {
            #pragma unroll
            for (int r = 0; r < 4; ++r) {
                const int row = m0 + wm + m * 16 + kq * 4 + r;
                float c = acc[m][n][r] + bv;
                if (mode == 0) {
                    c = fmaxf(c, 0.f);
                    unsigned short hi = f2bf(c);
                    unsigned short lo = f2bf(c - bf2f(hi));
                    Cp[(size_t)row * 2048 + col] = hi;
                    Cp[(size_t)row * 2048 + 1024 + col] = lo;
                } else {
                    Cf[(size_t)row * 1024 + col] = c;
                }
            }
        }
    }
}

// ---------------- out = LN(x + mlp_out, g2, b2) ----------------
__global__ void k_final(const unsigned short* __restrict__ Xp, const float* __restrict__ Y,
                        const float* __restrict__ g2, const float* __restrict__ b2,
                        float* __restrict__ out) {
    __shared__ float red[12];
    const int bq = blockIdx.x;
    const int tid = threadIdx.x;
    const int j = tid * 4;
    ushort4 xh = *(const ushort4*)&Xp[(size_t)bq * 2048 + j];
    ushort4 xl = *(const ushort4*)&Xp[(size_t)bq * 2048 + 1024 + j];
    float4 yv = *(const float4*)&Y[(size_t)bq * Dn + j];
    float xv[4];
    xv[0] = bf2f(xh.x) + bf2f(xl.x) + yv.x;
    xv[1] = bf2f(xh.y) + bf2f(xl.y) + yv.y;
    xv[2] = bf2f(xh.z) + bf2f(xl.z) + yv.z;
    xv[3] = bf2f(xh.w) + bf2f(xl.w) + yv.w;
    float lsum = xv[0] + xv[1] + xv[2] + xv[3];
    float lsq = xv[0]*xv[0] + xv[1]*xv[1] + xv[2]*xv[2] + xv[3]*xv[3];
    float mean, rstd;
    block_ln_stats(lsum, lsq, red, mean, rstd);
    float4 g = *(const float4*)&g2[j];
    float4 be = *(const float4*)&b2[j];
    float4 o;
    o.x = (xv[0] - mean) * rstd * g.x + be.x;
    o.y = (xv[1] - mean) * rstd * g.y + be.y;
    o.z = (xv[2] - mean) * rstd * g.z + be.z;
    o.w = (xv[3] - mean) * rstd * g.w + be.w;
    *(float4*)&out[(size_t)bq * Dn + j] = o;
}

extern "C" void kernel_launch(void* const* d_in, const int* in_sizes, int n_in,
                              void* d_out, int out_size, void* d_ws, size_t ws_size,
                              hipStream_t stream) {
    const float* key_in   = (const float*)d_in[0];
    const float* query_in = (const float*)d_in[1];
    const float* value_in = (const float*)d_in[2];
    const float* residual = (const float*)d_in[3];
    const float* Wk  = (const float*)d_in[4];
    const float* Wq  = (const float*)d_in[5];
    const float* Wv  = (const float*)d_in[6];
    const float* Wf  = (const float*)d_in[7];
    const float* bf  = (const float*)d_in[8];
    const float* g1  = (const float*)d_in[9];
    const float* b1  = (const float*)d_in[10];
    const float* Wm1 = (const float*)d_in[11];
    const float* bm1 = (const float*)d_in[12];
    const float* Wm2 = (const float*)d_in[13];
    const float* bm2 = (const float*)d_in[14];
    const float* Wm3 = (const float*)d_in[15];
    const float* bm3 = (const float*)d_in[16];
    const float* g2  = (const float*)d_in[17];
    const float* b2  = (const float*)d_in[18];
    float* ws  = (float*)d_ws;
    float* out = (float*)d_out;

    unsigned short* Xp  = (unsigned short*)(ws + OFF_X);
    unsigned short* H1p = (unsigned short*)(ws + OFF_H1);   // layer-1 output pair
    unsigned short* H2p = (unsigned short*)out;             // layer-2 output pair (d_out scratch)
    float*          Yf  = ws + OFF_H1;                      // layer-3 fp32 output (over H1p, dead)
    unsigned short* WT  = (unsigned short*)(ws + OFF_WT);

    // zero P/Cv/Sv/M/den accumulators (ws is poisoned 0xAA before every launch)
    hipMemsetAsync(ws + OFF_PC, 0, (size_t)(OFF_X - OFF_PC) * sizeof(float), stream);

    k_trig<<<512, 256, 0, stream>>>(key_in, query_in, Wk, Wq, ws);
    k_wsplit<<<dim3(16, 16, 3), 256, 0, stream>>>(Wm1, Wm2, Wm3, WT);
    k_phase<<<dim3(8, 4, 16), 256, 0, stream>>>(value_in, ws + OFF_CK, ws + OFF_SK,
                                                ws + OFF_PC, ws + OFF_PS);
    k_cv<<<dim3(64, 16), 128, 0, stream>>>(ws + OFF_PC, ws + OFF_PS, Wv,
                                           ws + OFF_CV, ws + OFF_SV);
    k_m<<<dim3(64, 4), 256, 0, stream>>>(ws + OFF_CV, ws + OFF_SV, Wf, ws + OFF_M);
    k_denom<<<dim3(8, 32, 2), 256, 0, stream>>>(ws, ws + OFF_DEN);
    k_x<<<8192, 256, 0, stream>>>(residual, bf, g1, b1, ws, Xp);

    // MLP via fused split-bf16 MFMA GEMMs
    gemm_split<<<512, 256, 0, stream>>>(Xp, WT, bm1, H1p, nullptr, 0);
    gemm_split<<<512, 256, 0, stream>>>(H1p, WT + 2097152, bm2, H2p, nullptr, 0);
    gemm_split<<<512, 256, 0, stream>>>(H2p, WT + 2 * 2097152, bm3, nullptr, Yf, 1);
    k_final<<<8192, 256, 0, stream>>>(Xp, Yf, g2, b2, out);
}

// Round 6
// 401.294 us; speedup vs baseline: 2.4657x; 1.0259x over previous
//
#include <hip/hip_runtime.h>
#include <math.h>

#define B_ 8
#define SQn 1024
#define SKn 1024
#define Dn 1024
#define Hn 8
#define DHn 128

// workspace float offsets
#define OFF_CQ 0
#define OFF_SQ 65536
#define OFF_CK 131072
#define OFF_SK 196608
#define OFF_PC 262144
#define OFF_PS 327680
#define OFF_CV 393216
#define OFF_SV 401408
#define OFF_M  409600
#define OFF_DEN 540672
#define OFF_X  606208      // Xpair: 8192 x 2048 bf16 = 8M float slots
#define OFF_H1 8994816     // H1pair (bf16) / Y (bf16 single): 8M float slots
#define OFF_WT 17383424    // 3 weight pairs, each 1024x2048 bf16 = 1M float slots
// total: 20530176 floats = 78.3 MiB

typedef __attribute__((ext_vector_type(8))) short short8;
typedef __attribute__((ext_vector_type(4))) float f32x4;

__device__ __forceinline__ unsigned short f2bf(float f) {
    unsigned int u = __float_as_uint(f);
    unsigned int r = (u + 0x7fffu + ((u >> 16) & 1u)) >> 16;
    return (unsigned short)r;
}
__device__ __forceinline__ float bf2f(unsigned short h) {
    return __uint_as_float(((unsigned int)h) << 16);
}

__device__ __forceinline__ void gld16(const unsigned short* g, unsigned short* l) {
    __builtin_amdgcn_global_load_lds(
        (const __attribute__((address_space(1))) void*)g,
        (__attribute__((address_space(3))) void*)l, 16, 0, 0);
}

// ---------------- fused prep: trig + weight split + zero accumulators ----------------
// blocks [0,512): per-head scalar q/k trig
// blocks [512,1280): weight transpose + bf16 hi/lo split (3 x 16 x 16)
// blocks [1280,1364): zero ws[OFF_PC..OFF_X)
__global__ void k_prep(const float* __restrict__ key_in, const float* __restrict__ query_in,
                       const float* __restrict__ Wk, const float* __restrict__ Wq,
                       const float* __restrict__ W0, const float* __restrict__ W1,
                       const float* __restrict__ W2, float* __restrict__ ws,
                       unsigned short* __restrict__ wt) {
    __shared__ float tile[64][65];
    const int bid = blockIdx.x;
    const int tid = threadIdx.x;
    if (bid < 512) {
        int idx = bid * 256 + tid;                       // 131072 threads
        const int n = B_ * SQn * Hn;                     // 65536
        if (idx < n) {
            int h = idx & 7, bs = idx >> 3;
            float v = query_in[bs] * Wq[h];
            ws[OFF_CQ + idx] = cosf(v);
            ws[OFF_SQ + idx] = sinf(v);
        } else {
            int i2 = idx - n;
            int h = i2 & 7, bs = i2 >> 3;
            float v = key_in[bs] * Wk[h];
            ws[OFF_CK + i2] = cosf(v);
            ws[OFF_SK + i2] = sinf(v);
        }
    } else if (bid < 1280) {
        const int zb = bid - 512;
        const int z = zb >> 8, r = zb & 255;
        const float* W = (z == 0) ? W0 : (z == 1) ? W1 : W2;
        unsigned short* out = wt + (size_t)z * 2097152;
        const int k0 = (r & 15) * 64, n0 = (r >> 4) * 64;
        const int tx = tid & 63, ty = tid >> 6;          // 64 x 4
        #pragma unroll
        for (int i = 0; i < 16; ++i) {
            int rr = ty + i * 4;
            tile[rr][tx] = W[(size_t)(k0 + rr) * Dn + n0 + tx];
        }
        __syncthreads();
        #pragma unroll
        for (int i = 0; i < 16; ++i) {
            int rr = ty + i * 4;                // n - n0
            float v = tile[tx][rr];             // W^T[n0+rr][k0+tx]
            unsigned short hi = f2bf(v);
            unsigned short lo = f2bf(v - bf2f(hi));
            out[(size_t)(n0 + rr) * 2048 + k0 + tx] = hi;
            out[(size_t)(n0 + rr) * 2048 + 1024 + k0 + tx] = lo;
        }
    } else {
        const int zb = bid - 1280;                       // 84 blocks
        float4* p = (float4*)(ws + OFF_PC);              // 86016 float4s
        p[zb * 256 + tid] = (float4){0.f, 0.f, 0.f, 0.f};
    }
}

// ---------------- P[b,h,i] = sum_k trig(k)*value_in[b,k,i] ----------------
// grid (8, 4, 16): b, i-chunk(256), k-chunk(64)
__global__ void k_phase(const float* __restrict__ value_in, const float* __restrict__ ck,
                        const float* __restrict__ sk, float* __restrict__ Pc,
                        float* __restrict__ Ps) {
    __shared__ __align__(16) float ckk[512];
    __shared__ __align__(16) float skk[512];
    const int b = blockIdx.x, it = blockIdx.y, kc = blockIdx.z;
    const int tid = threadIdx.x;
    const int base = (b * SKn + kc * 64) * Hn;
    *(float2*)&ckk[tid * 2] = *(const float2*)&ck[base + tid * 2];
    *(float2*)&skk[tid * 2] = *(const float2*)&sk[base + tid * 2];
    __syncthreads();
    const int i = it * 256 + tid;
    float aC[8] = {0,0,0,0,0,0,0,0}, aS[8] = {0,0,0,0,0,0,0,0};
    const float* vp = value_in + (size_t)(b * SKn + kc * 64) * Dn + i;
    #pragma unroll 4
    for (int kk = 0; kk < 64; ++kk) {
        float v = vp[(size_t)kk * Dn];
        float4 c0 = *(const float4*)&ckk[kk * 8];
        float4 c1 = *(const float4*)&ckk[kk * 8 + 4];
        float4 s0 = *(const float4*)&skk[kk * 8];
        float4 s1 = *(const float4*)&skk[kk * 8 + 4];
        aC[0] = fmaf(v, c0.x, aC[0]); aC[1] = fmaf(v, c0.y, aC[1]);
        aC[2] = fmaf(v, c0.z, aC[2]); aC[3] = fmaf(v, c0.w, aC[3]);
        aC[4] = fmaf(v, c1.x, aC[4]); aC[5] = fmaf(v, c1.y, aC[5]);
        aC[6] = fmaf(v, c1.z, aC[6]); aC[7] = fmaf(v, c1.w, aC[7]);
        aS[0] = fmaf(v, s0.x, aS[0]); aS[1] = fmaf(v, s0.y, aS[1]);
        aS[2] = fmaf(v, s0.z, aS[2]); aS[3] = fmaf(v, s0.w, aS[3]);
        aS[4] = fmaf(v, s1.x, aS[4]); aS[5] = fmaf(v, s1.y, aS[5]);
        aS[6] = fmaf(v, s1.z, aS[6]); aS[7] = fmaf(v, s1.w, aS[7]);
    }
    #pragma unroll
    for (int h = 0; h < 8; ++h) {
        atomicAdd(&Pc[(b * Hn + h) * Dn + i], aC[h]);
        atomicAdd(&Ps[(b * Hn + h) * Dn + i], aS[h]);
    }
}

// ---------------- Cv/Sv[b,h,d] = sum_i P[b,h,i]*Wv[i, h*128+d] ----------------
// grid (64, 16): bh, i-chunk(64)
__global__ void k_cv(const float* __restrict__ Pc, const float* __restrict__ Ps,
                     const float* __restrict__ Wv, float* __restrict__ Cv,
                     float* __restrict__ Sv) {
    const int bh = blockIdx.x;
    const int ic = blockIdx.y;
    const int h = bh & 7;
    const int d = threadIdx.x;     // 128
    float ac = 0.f, as = 0.f;
    const float* wp = Wv + (size_t)(ic * 64) * Dn + h * DHn + d;
    const float* pc = Pc + bh * Dn + ic * 64;
    const float* ps = Ps + bh * Dn + ic * 64;
    #pragma unroll 4
    for (int i = 0; i < 64; ++i) {
        float w = wp[(size_t)i * Dn];
        ac = fmaf(pc[i], w, ac);
        as = fmaf(ps[i], w, as);
    }
    atomicAdd(&Cv[bh * DHn + d], ac);
    atomicAdd(&Sv[bh * DHn + d], as);
}

// ---------------- M[b,t,j]: t=h -> Cv@Wf slice, t=8+h -> Sv@Wf slice ----------------
__global__ void k_m(const float* __restrict__ Cv, const float* __restrict__ Sv,
                    const float* __restrict__ Wf, float* __restrict__ M) {
    const int bh = blockIdx.x;
    const int dc = blockIdx.y;     // 4 chunks of 32 d's
    const int b = bh >> 3, h = bh & 7;
    const int j = threadIdx.x * 4;
    float4 ac = {0,0,0,0}, as = {0,0,0,0};
    #pragma unroll 4
    for (int dd = 0; dd < 32; ++dd) {
        int d = dc * 32 + dd;
        float cv = Cv[bh * DHn + d];
        float sv = Sv[bh * DHn + d];
        float4 w = *(const float4*)&Wf[(size_t)(h * DHn + d) * Dn + j];
        ac.x = fmaf(cv, w.x, ac.x); ac.y = fmaf(cv, w.y, ac.y);
        ac.z = fmaf(cv, w.z, ac.z); ac.w = fmaf(cv, w.w, ac.w);
        as.x = fmaf(sv, w.x, as.x); as.y = fmaf(sv, w.y, as.y);
        as.z = fmaf(sv, w.z, as.z); as.w = fmaf(sv, w.w, as.w);
    }
    float* mc = &M[(size_t)(b * 16 + h) * Dn + j];
    float* ms = &M[(size_t)(b * 16 + 8 + h) * Dn + j];
    atomicAdd(mc + 0, ac.x); atomicAdd(mc + 1, ac.y);
    atomicAdd(mc + 2, ac.z); atomicAdd(mc + 3, ac.w);
    atomicAdd(ms + 0, as.x); atomicAdd(ms + 1, as.y);
    atomicAdd(ms + 2, as.z); atomicAdd(ms + 3, as.w);
}

// ---------------- denom partial: atomicAdd sum_k |cq*ck + sq*sk| ----------------
// grid (8, 32, 2)
__global__ void k_denom(const float* __restrict__ ws, float* __restrict__ den) {
    __shared__ __align__(16) float ckk[8][132];
    __shared__ __align__(16) float skk[8][132];
    const int b = blockIdx.x, qt = blockIdx.y, zh = blockIdx.z;
    const int tid = threadIdx.x;
    const int qq = tid >> 3, h = tid & 7;
    const int q = qt * 32 + qq;
    const float cqv = ws[OFF_CQ + (b * SQn + q) * Hn + h];
    const float sqv = ws[OFF_SQ + (b * SQn + q) * Hn + h];
    float acc = 0.f;
    for (int kc = zh * 4; kc < zh * 4 + 4; ++kc) {
        __syncthreads();
        const int base = (b * SKn + kc * 128) * Hn;
        float4 c4 = *(const float4*)&ws[OFF_CK + base + tid * 4];
        float4 s4 = *(const float4*)&ws[OFF_SK + base + tid * 4];
        #pragma unroll
        for (int u = 0; u < 4; ++u) {
            int f = tid * 4 + u;
            ckk[f & 7][f >> 3] = ((const float*)&c4)[u];
            skk[f & 7][f >> 3] = ((const float*)&s4)[u];
        }
        __syncthreads();
        #pragma unroll
        for (int kv = 0; kv < 32; ++kv) {
            float4 c = *(const float4*)&ckk[h][kv * 4];
            float4 s = *(const float4*)&skk[h][kv * 4];
            acc += fabsf(cqv * c.x + sqv * s.x);
            acc += fabsf(cqv * c.y + sqv * s.y);
            acc += fabsf(cqv * c.z + sqv * s.z);
            acc += fabsf(cqv * c.w + sqv * s.w);
        }
    }
    atomicAdd(&den[(b * SQn + q) * Hn + h], acc);
}

// ---------------- block LayerNorm stats helper ----------------
__device__ inline void block_ln_stats(float lsum, float lsq, float* red,
                                      float& mean, float& rstd) {
    #pragma unroll
    for (int off = 32; off; off >>= 1) {
        lsum += __shfl_xor(lsum, off);
        lsq  += __shfl_xor(lsq, off);
    }
    const int wid = threadIdx.x >> 6;
    if ((threadIdx.x & 63) == 0) { red[wid * 2] = lsum; red[wid * 2 + 1] = lsq; }
    __syncthreads();
    if (threadIdx.x == 0) {
        float s  = red[0] + red[2] + red[4] + red[6];
        float ss = red[1] + red[3] + red[5] + red[7];
        float m = s * (1.0f / Dn);
        red[8] = m;
        red[9] = rsqrtf(ss * (1.0f / Dn) - m * m + 1e-5f);
    }
    __syncthreads();
    mean = red[8];
    rstd = red[9];
}

// ---------------- x = LN(residual + rank16-combine + bf) -> bf16 hi/lo pair ----------------
__global__ void k_x(const float* __restrict__ residual, const float* __restrict__ bf,
                    const float* __restrict__ g1, const float* __restrict__ b1,
                    const float* __restrict__ ws, unsigned short* __restrict__ Xp) {
    __shared__ float lcoef[16];
    __shared__ float red[12];
    const int bq = blockIdx.x;       // b*SQ + q
    const int b = bq >> 10;
    const int tid = threadIdx.x;
    if (tid < 8) {
        float dinv = 1.0f / (ws[OFF_DEN + bq * Hn + tid] + 1e-6f);
        lcoef[tid]     = ws[OFF_CQ + bq * Hn + tid] * dinv;
        lcoef[8 + tid] = ws[OFF_SQ + bq * Hn + tid] * dinv;
    }
    __syncthreads();
    const int j = tid * 4;
    float4 acc = *(const float4*)&bf[j];
    const float* Mp = ws + OFF_M + (size_t)b * 16 * Dn + j;
    #pragma unroll
    for (int t = 0; t < 16; ++t) {
        float cf = lcoef[t];
        float4 m4 = *(const float4*)&Mp[(size_t)t * Dn];
        acc.x = fmaf(cf, m4.x, acc.x); acc.y = fmaf(cf, m4.y, acc.y);
        acc.z = fmaf(cf, m4.z, acc.z); acc.w = fmaf(cf, m4.w, acc.w);
    }
    float4 r = *(const float4*)&residual[(size_t)bq * Dn + j];
    acc.x += r.x; acc.y += r.y; acc.z += r.z; acc.w += r.w;
    float lsum = acc.x + acc.y + acc.z + acc.w;
    float lsq = acc.x * acc.x + acc.y * acc.y + acc.z * acc.z + acc.w * acc.w;
    float mean, rstd;
    block_ln_stats(lsum, lsq, red, mean, rstd);
    float4 g = *(const float4*)&g1[j];
    float4 be = *(const float4*)&b1[j];
    float o[4];
    o[0] = (acc.x - mean) * rstd * g.x + be.x;
    o[1] = (acc.y - mean) * rstd * g.y + be.y;
    o[2] = (acc.z - mean) * rstd * g.z + be.z;
    o[3] = (acc.w - mean) * rstd * g.w + be.w;
    ushort4 hi, lo;
    unsigned short* hp = (unsigned short*)&hi;
    unsigned short* lp = (unsigned short*)&lo;
    #pragma unroll
    for (int u = 0; u < 4; ++u) {
        hp[u] = f2bf(o[u]);
        lp[u] = f2bf(o[u] - bf2f(hp[u]));
    }
    *(ushort4*)&Xp[(size_t)bq * 2048 + j] = hi;
    *(ushort4*)&Xp[(size_t)bq * 2048 + 1024 + j] = lo;
}

// ---------------- fused 3-term split-bf16 MFMA GEMM, half-k ping-pong ----------------
// C = act( (Ah+Al) @ (Wh+Wl)^T + bias ), terms Ah*Wh + Al*Wh + Ah*Wl.
// Half-k (32-wide) double-buffered staging: stage half t+1 before compute of
// half t; one barrier per half. LDS 2 bufs x 4 operands x 128x32 = 64 KB.
// mode 0: bf16 pair + relu -> Cp ; mode 1: single bf16 (no relu) -> Cb
__global__ __launch_bounds__(256) void gemm_split(const unsigned short* __restrict__ Ap,
                                                  const unsigned short* __restrict__ Wp,
                                                  const float* __restrict__ bias,
                                                  unsigned short* __restrict__ Cp,
                                                  unsigned short* __restrict__ Cb, int mode) {
    __shared__ __align__(16) unsigned short buf[2][4][128 * 32];
    const int t = threadIdx.x;
    // XCD-locality swizzle: XCD c (= orig&7, round-robin) owns m-blocks [8c,8c+8)
    // -> per-XCD A working set 4 MB (L2-resident), W-panel hot per 8-block window
    const int orig = blockIdx.x;
    const int c = orig & 7, g = orig >> 3;
    const int m0 = (c * 8 + (g & 7)) * 128;
    const int n0 = (g >> 3) * 128;

    const int w = t >> 6;          // wave 0..3
    const int wm = (w >> 1) * 64;
    const int wn = (w & 1) * 64;
    const int l15 = t & 15;
    const int kq = (t >> 4) & 3;

    const int tr2 = t >> 2;        // staging row 0..63
    const int tc2 = (t & 3) * 8;   // staging col (elements, within 32)

    f32x4 acc[4][4];
    #pragma unroll
    for (int m = 0; m < 4; ++m)
        #pragma unroll
        for (int n = 0; n < 4; ++n)
            acc[m][n] = (f32x4){0.f, 0.f, 0.f, 0.f};

#define STAGE(pp, kh) do {                                                          \
        const int k0_ = (kh) * 32;                                                  \
        _Pragma("unroll")                                                           \
        for (int i_ = 0; i_ < 2; ++i_) {                                            \
            const int row_ = i_ * 64 + tr2;                                         \
            gld16(Ap + (size_t)(m0 + row_) * 2048 + k0_ + tc2,                      \
                  &buf[pp][0][row_ * 32 + tc2]);                                    \
            gld16(Ap + (size_t)(m0 + row_) * 2048 + 1024 + k0_ + tc2,               \
                  &buf[pp][1][row_ * 32 + tc2]);                                    \
            gld16(Wp + (size_t)(n0 + row_) * 2048 + k0_ + tc2,                      \
                  &buf[pp][2][row_ * 32 + tc2]);                                    \
            gld16(Wp + (size_t)(n0 + row_) * 2048 + 1024 + k0_ + tc2,               \
                  &buf[pp][3][row_ * 32 + tc2]);                                    \
        }                                                                           \
    } while (0)

    STAGE(0, 0);
    __syncthreads();                       // drain prologue stage
    for (int kh = 0; kh < 32; ++kh) {
        const int cur = kh & 1;
        if (kh < 31) STAGE(cur ^ 1, kh + 1);   // prefetch next half (vmem in flight)
        short8 afh[4], afl[4], bfh[4], bfl[4];
        #pragma unroll
        for (int m = 0; m < 4; ++m) {
            const int ro = (wm + m * 16 + l15) * 32 + kq * 8;
            afh[m] = *(const short8*)&buf[cur][0][ro];
            afl[m] = *(const short8*)&buf[cur][1][ro];
        }
        #pragma unroll
        for (int n = 0; n < 4; ++n) {
            const int ro = (wn + n * 16 + l15) * 32 + kq * 8;
            bfh[n] = *(const short8*)&buf[cur][2][ro];
            bfl[n] = *(const short8*)&buf[cur][3][ro];
        }
        #pragma unroll
        for (int m = 0; m < 4; ++m)
            #pragma unroll
            for (int n = 0; n < 4; ++n) {
                acc[m][n] = __builtin_amdgcn_mfma_f32_16x16x32_bf16(
                    afh[m], bfh[n], acc[m][n], 0, 0, 0);
                acc[m][n] = __builtin_amdgcn_mfma_f32_16x16x32_bf16(
                    afl[m], bfh[n], acc[m][n], 0, 0, 0);
                acc[m][n] = __builtin_amdgcn_mfma_f32_16x16x32_bf16(
                    afh[m], bfl[n], acc[m][n], 0, 0, 0);
            }
        __syncthreads();   // readers of buf[cur] done + prefetch writes drained
    }
#undef STAGE

    // epilogue
    #pragma unroll
    for (int n = 0; n < 4; ++n) {
        const int col = n0 + wn + n * 16 + l15;
        const float bv = bias[col];
        #pragma unroll
        for (int m = 0; m < 4; ++m) {
            #pragma unroll
            for (int r = 0; r < 4; ++r) {
                const int row = m0 + wm + m * 16 + kq * 4 + r;
                float cc = acc[m][n][r] + bv;
                if (mode == 0) {
                    cc = fmaxf(cc, 0.f);
                    unsigned short hi = f2bf(cc);
                    unsigned short lo = f2bf(cc - bf2f(hi));
                    Cp[(size_t)row * 2048 + col] = hi;
                    Cp[(size_t)row * 2048 + 1024 + col] = lo;
                } else {
                    Cb[(size_t)row * 1024 + col] = f2bf(cc);
                }
            }
        }
    }
}

// ---------------- out = LN(x + mlp_out, g2, b2) ----------------
__global__ void k_final(const unsigned short* __restrict__ Xp,
                        const unsigned short* __restrict__ Y,
                        const float* __restrict__ g2, const float* __restrict__ b2,
                        float* __restrict__ out) {
    __shared__ float red[12];
    const int bq = blockIdx.x;
    const int tid = threadIdx.x;
    const int j = tid * 4;
    ushort4 xh = *(const ushort4*)&Xp[(size_t)bq * 2048 + j];
    ushort4 xl = *(const ushort4*)&Xp[(size_t)bq * 2048 + 1024 + j];
    ushort4 yv = *(const ushort4*)&Y[(size_t)bq * 1024 + j];
    float xv[4];
    xv[0] = bf2f(xh.x) + bf2f(xl.x) + bf2f(yv.x);
    xv[1] = bf2f(xh.y) + bf2f(xl.y) + bf2f(yv.y);
    xv[2] = bf2f(xh.z) + bf2f(xl.z) + bf2f(yv.z);
    xv[3] = bf2f(xh.w) + bf2f(xl.w) + bf2f(yv.w);
    float lsum = xv[0] + xv[1] + xv[2] + xv[3];
    float lsq = xv[0]*xv[0] + xv[1]*xv[1] + xv[2]*xv[2] + xv[3]*xv[3];
    float mean, rstd;
    block_ln_stats(lsum, lsq, red, mean, rstd);
    float4 g = *(const float4*)&g2[j];
    float4 be = *(const float4*)&b2[j];
    float4 o;
    o.x = (xv[0] - mean) * rstd * g.x + be.x;
    o.y = (xv[1] - mean) * rstd * g.y + be.y;
    o.z = (xv[2] - mean) * rstd * g.z + be.z;
    o.w = (xv[3] - mean) * rstd * g.w + be.w;
    *(float4*)&out[(size_t)bq * Dn + j] = o;
}

extern "C" void kernel_launch(void* const* d_in, const int* in_sizes, int n_in,
                              void* d_out, int out_size, void* d_ws, size_t ws_size,
                              hipStream_t stream) {
    const float* key_in   = (const float*)d_in[0];
    const float* query_in = (const float*)d_in[1];
    const float* value_in = (const float*)d_in[2];
    const float* residual = (const float*)d_in[3];
    const float* Wk  = (const float*)d_in[4];
    const float* Wq  = (const float*)d_in[5];
    const float* Wv  = (const float*)d_in[6];
    const float* Wf  = (const float*)d_in[7];
    const float* bf  = (const float*)d_in[8];
    const float* g1  = (const float*)d_in[9];
    const float* b1  = (const float*)d_in[10];
    const float* Wm1 = (const float*)d_in[11];
    const float* bm1 = (const float*)d_in[12];
    const float* Wm2 = (const float*)d_in[13];
    const float* bm2 = (const float*)d_in[14];
    const float* Wm3 = (const float*)d_in[15];
    const float* bm3 = (const float*)d_in[16];
    const float* g2  = (const float*)d_in[17];
    const float* b2  = (const float*)d_in[18];
    float* ws  = (float*)d_ws;
    float* out = (float*)d_out;

    unsigned short* Xp  = (unsigned short*)(ws + OFF_X);
    unsigned short* H1p = (unsigned short*)(ws + OFF_H1);   // layer-1 output pair
    unsigned short* H2p = (unsigned short*)out;             // layer-2 output pair (d_out scratch)
    unsigned short* Yb  = (unsigned short*)(ws + OFF_H1);   // layer-3 bf16 output (over H1p, dead)
    unsigned short* WT  = (unsigned short*)(ws + OFF_WT);

    // prep: trig + weight split + zero accumulators (ws poisoned 0xAA pre-launch)
    k_prep<<<1364, 256, 0, stream>>>(key_in, query_in, Wk, Wq, Wm1, Wm2, Wm3, ws, WT);
    k_phase<<<dim3(8, 4, 16), 256, 0, stream>>>(value_in, ws + OFF_CK, ws + OFF_SK,
                                                ws + OFF_PC, ws + OFF_PS);
    k_cv<<<dim3(64, 16), 128, 0, stream>>>(ws + OFF_PC, ws + OFF_PS, Wv,
                                           ws + OFF_CV, ws + OFF_SV);
    k_m<<<dim3(64, 4), 256, 0, stream>>>(ws + OFF_CV, ws + OFF_SV, Wf, ws + OFF_M);
    k_denom<<<dim3(8, 32, 2), 256, 0, stream>>>(ws, ws + OFF_DEN);
    k_x<<<8192, 256, 0, stream>>>(residual, bf, g1, b1, ws, Xp);

    // MLP via fused split-bf16 MFMA GEMMs (half-k ping-pong pipeline)
    gemm_split<<<512, 256, 0, stream>>>(Xp, WT, bm1, H1p, nullptr, 0);
    gemm_split<<<512, 256, 0, stream>>>(H1p, WT + 2097152, bm2, H2p, nullptr, 0);
    gemm_split<<<512, 256, 0, stream>>>(H2p, WT + 2 * 2097152, bm3, nullptr, Yb, 1);
    k_final<<<8192, 256, 0, stream>>>(Xp, Yb, g2, b2, out);
}

// Round 11
// 394.959 us; speedup vs baseline: 2.5052x; 1.0160x over previous
//
#include <hip/hip_runtime.h>
#include <math.h>

#define B_ 8
#define SQn 1024
#define SKn 1024
#define Dn 1024
#define Hn 8
#define DHn 128

// workspace float offsets
#define OFF_CQ 0
#define OFF_SQ 65536
#define OFF_CK 131072
#define OFF_SK 196608
#define OFF_CV 393216
#define OFF_SV 401408
#define OFF_M  409600
#define OFF_DEN 540672
#define OFF_X  606208      // Xpair: 8192 x 2048 bf16 = 8M float slots (P_part early)
#define OFF_H1 8994816     // H1pair (bf16) / Y (bf16 single): 8M float slots
#define OFF_WT 17383424    // 3 weight pairs, each 1024x2048 bf16 = 1M float slots
// total: 20530176 floats = 78.3 MiB

typedef __attribute__((ext_vector_type(8))) short short8;
typedef __attribute__((ext_vector_type(4))) float f32x4;

__device__ __forceinline__ unsigned short f2bf(float f) {
    unsigned int u = __float_as_uint(f);
    unsigned int r = (u + 0x7fffu + ((u >> 16) & 1u)) >> 16;
    return (unsigned short)r;
}
__device__ __forceinline__ float bf2f(unsigned short h) {
    return __uint_as_float(((unsigned int)h) << 16);
}

__device__ __forceinline__ void gld16(const unsigned short* g, unsigned short* l) {
    __builtin_amdgcn_global_load_lds(
        (const __attribute__((address_space(1))) void*)g,
        (__attribute__((address_space(3))) void*)l, 16, 0, 0);
}

// ---------------- fused prep: trig + weight split + zero accumulators ----------------
// blocks [0,512): per-head scalar q/k trig
// blocks [512,1280): weight transpose + bf16 hi/lo split (3 x 256)
// blocks [1280,1488): zero ws[OFF_CV..OFF_X)  (Cv/Sv/M/den atomic targets)
__global__ void k_prep(const float* __restrict__ key_in, const float* __restrict__ query_in,
                       const float* __restrict__ Wk, const float* __restrict__ Wq,
                       const float* __restrict__ W0, const float* __restrict__ W1,
                       const float* __restrict__ W2, float* __restrict__ ws,
                       unsigned short* __restrict__ wt) {
    __shared__ float tile[64][65];
    const int bid = blockIdx.x;
    const int tid = threadIdx.x;
    if (bid < 512) {
        int idx = bid * 256 + tid;                       // 131072 threads
        const int n = B_ * SQn * Hn;                     // 65536
        if (idx < n) {
            int h = idx & 7, bs = idx >> 3;
            float v = query_in[bs] * Wq[h];
            ws[OFF_CQ + idx] = cosf(v);
            ws[OFF_SQ + idx] = sinf(v);
        } else {
            int i2 = idx - n;
            int h = i2 & 7, bs = i2 >> 3;
            float v = key_in[bs] * Wk[h];
            ws[OFF_CK + i2] = cosf(v);
            ws[OFF_SK + i2] = sinf(v);
        }
    } else if (bid < 1280) {
        const int zb = bid - 512;
        const int z = zb >> 8, r = zb & 255;
        const float* W = (z == 0) ? W0 : (z == 1) ? W1 : W2;
        unsigned short* out = wt + (size_t)z * 2097152;
        const int k0 = (r & 15) * 64, n0 = (r >> 4) * 64;
        const int tx = tid & 63, ty = tid >> 6;          // 64 x 4
        #pragma unroll
        for (int i = 0; i < 16; ++i) {
            int rr = ty + i * 4;
            tile[rr][tx] = W[(size_t)(k0 + rr) * Dn + n0 + tx];
        }
        __syncthreads();
        #pragma unroll
        for (int i = 0; i < 16; ++i) {
            int rr = ty + i * 4;                // n - n0
            float v = tile[tx][rr];             // W^T[n0+rr][k0+tx]
            unsigned short hi = f2bf(v);
            unsigned short lo = f2bf(v - bf2f(hi));
            out[(size_t)(n0 + rr) * 2048 + k0 + tx] = hi;
            out[(size_t)(n0 + rr) * 2048 + 1024 + k0 + tx] = lo;
        }
    } else {
        const int zb = bid - 1280;                       // 208 blocks
        float4* p = (float4*)(ws + OFF_CV);              // 53248 float4s
        p[zb * 256 + tid] = (float4){0.f, 0.f, 0.f, 0.f};
    }
}

// ---------------- merged phase + denom ----------------
// blocks [0,512): P_part[kc][bh][i] = sum_{k in chunk} trig(k)*value_in[b,k,i]
// blocks [512,1024): den[b,q,h] += sum_k |cq*ck + sq*sk|  (atomic partials)
__global__ void k_pd(const float* __restrict__ value_in, const float* __restrict__ ws,
                     float* __restrict__ Pcp, float* __restrict__ Psp,
                     float* __restrict__ den) {
    __shared__ __align__(16) float sA[8][132];
    __shared__ __align__(16) float sB[8][132];
    const int bid = blockIdx.x;
    const int tid = threadIdx.x;
    if (bid < 512) {
        // phase: b = bid&7, it = (bid>>3)&3, kc = bid>>5
        const int b = bid & 7, it = (bid >> 3) & 3, kc = bid >> 5;
        float* ckk = (float*)sA;     // 512 floats
        float* skk = (float*)sB;
        const float* ck = ws + OFF_CK;
        const float* sk = ws + OFF_SK;
        const int base = (b * SKn + kc * 64) * Hn;
        *(float2*)&ckk[tid * 2] = *(const float2*)&ck[base + tid * 2];
        *(float2*)&skk[tid * 2] = *(const float2*)&sk[base + tid * 2];
        __syncthreads();
        const int i = it * 256 + tid;
        float aC[8] = {0,0,0,0,0,0,0,0}, aS[8] = {0,0,0,0,0,0,0,0};
        const float* vp = value_in + (size_t)(b * SKn + kc * 64) * Dn + i;
        #pragma unroll 4
        for (int kk = 0; kk < 64; ++kk) {
            float v = vp[(size_t)kk * Dn];
            float4 c0 = *(const float4*)&ckk[kk * 8];
            float4 c1 = *(const float4*)&ckk[kk * 8 + 4];
            float4 s0 = *(const float4*)&skk[kk * 8];
            float4 s1 = *(const float4*)&skk[kk * 8 + 4];
            aC[0] = fmaf(v, c0.x, aC[0]); aC[1] = fmaf(v, c0.y, aC[1]);
            aC[2] = fmaf(v, c0.z, aC[2]); aC[3] = fmaf(v, c0.w, aC[3]);
            aC[4] = fmaf(v, c1.x, aC[4]); aC[5] = fmaf(v, c1.y, aC[5]);
            aC[6] = fmaf(v, c1.z, aC[6]); aC[7] = fmaf(v, c1.w, aC[7]);
            aS[0] = fmaf(v, s0.x, aS[0]); aS[1] = fmaf(v, s0.y, aS[1]);
            aS[2] = fmaf(v, s0.z, aS[2]); aS[3] = fmaf(v, s0.w, aS[3]);
            aS[4] = fmaf(v, s1.x, aS[4]); aS[5] = fmaf(v, s1.y, aS[5]);
            aS[6] = fmaf(v, s1.z, aS[6]); aS[7] = fmaf(v, s1.w, aS[7]);
        }
        #pragma unroll
        for (int h = 0; h < 8; ++h) {
            Pcp[(size_t)(kc * 64 + b * 8 + h) * 1024 + i] = aC[h];
            Psp[(size_t)(kc * 64 + b * 8 + h) * 1024 + i] = aS[h];
        }
    } else {
        // denom: v = bid-512; b = v&7, qt = (v>>3)&31, zh = v>>8
        const int v = bid - 512;
        const int b = v & 7, qt = (v >> 3) & 31, zh = v >> 8;
        const int qq = tid >> 3, h = tid & 7;
        const int q = qt * 32 + qq;
        const float cqv = ws[OFF_CQ + (b * SQn + q) * Hn + h];
        const float sqv = ws[OFF_SQ + (b * SQn + q) * Hn + h];
        float acc = 0.f;
        for (int kc = zh * 4; kc < zh * 4 + 4; ++kc) {
            __syncthreads();
            const int base = (b * SKn + kc * 128) * Hn;
            float4 c4 = *(const float4*)&ws[OFF_CK + base + tid * 4];
            float4 s4 = *(const float4*)&ws[OFF_SK + base + tid * 4];
            #pragma unroll
            for (int u = 0; u < 4; ++u) {
                int f = tid * 4 + u;
                sA[f & 7][f >> 3] = ((const float*)&c4)[u];
                sB[f & 7][f >> 3] = ((const float*)&s4)[u];
            }
            __syncthreads();
            #pragma unroll
            for (int kv = 0; kv < 32; ++kv) {
                float4 c = *(const float4*)&sA[h][kv * 4];
                float4 s = *(const float4*)&sB[h][kv * 4];
                acc += fabsf(cqv * c.x + sqv * s.x);
                acc += fabsf(cqv * c.y + sqv * s.y);
                acc += fabsf(cqv * c.z + sqv * s.z);
                acc += fabsf(cqv * c.w + sqv * s.w);
            }
        }
        atomicAdd(&den[(b * SQn + q) * Hn + h], acc);
    }
}

// ---------------- Cv/Sv[b,h,d] = sum_i (sum_kc P_part) * Wv[i, h*128+d] ----------------
// grid (64, 16), 128 threads: bh, i-chunk(64)
__global__ void k_cv(const float* __restrict__ Pcp, const float* __restrict__ Psp,
                     const float* __restrict__ Wv, float* __restrict__ Cv,
                     float* __restrict__ Sv) {
    __shared__ float pc2[2][64];
    __shared__ float ps2[2][64];
    const int bh = blockIdx.x;
    const int ic = blockIdx.y;
    const int h = bh & 7;
    const int t = threadIdx.x;     // 128
    // stage: reduce 16 kc-partials for this 64-i chunk into LDS
    {
        const int ii = t & 63, kh2 = t >> 6;   // kh2 in {0,1}: 8 kc's each
        float sc = 0.f, ss = 0.f;
        #pragma unroll
        for (int kc = kh2 * 8; kc < kh2 * 8 + 8; ++kc) {
            sc += Pcp[(size_t)(kc * 64 + bh) * 1024 + ic * 64 + ii];
            ss += Psp[(size_t)(kc * 64 + bh) * 1024 + ic * 64 + ii];
        }
        pc2[kh2][ii] = sc;
        ps2[kh2][ii] = ss;
    }
    __syncthreads();
    const int d = t;
    float ac = 0.f, as = 0.f;
    const float* wp = Wv + (size_t)(ic * 64) * Dn + h * DHn + d;
    #pragma unroll 4
    for (int i = 0; i < 64; ++i) {
        float w = wp[(size_t)i * Dn];
        ac = fmaf(pc2[0][i] + pc2[1][i], w, ac);
        as = fmaf(ps2[0][i] + ps2[1][i], w, as);
    }
    atomicAdd(&Cv[bh * DHn + d], ac);
    atomicAdd(&Sv[bh * DHn + d], as);
}

// ---------------- M[b,t,j]: t=h -> Cv@Wf slice, t=8+h -> Sv@Wf slice ----------------
__global__ void k_m(const float* __restrict__ Cv, const float* __restrict__ Sv,
                    const float* __restrict__ Wf, float* __restrict__ M) {
    const int bh = blockIdx.x;
    const int dc = blockIdx.y;     // 4 chunks of 32 d's
    const int b = bh >> 3, h = bh & 7;
    const int j = threadIdx.x * 4;
    float4 ac = {0,0,0,0}, as = {0,0,0,0};
    #pragma unroll 4
    for (int dd = 0; dd < 32; ++dd) {
        int d = dc * 32 + dd;
        float cv = Cv[bh * DHn + d];
        float sv = Sv[bh * DHn + d];
        float4 w = *(const float4*)&Wf[(size_t)(h * DHn + d) * Dn + j];
        ac.x = fmaf(cv, w.x, ac.x); ac.y = fmaf(cv, w.y, ac.y);
        ac.z = fmaf(cv, w.z, ac.z); ac.w = fmaf(cv, w.w, ac.w);
        as.x = fmaf(sv, w.x, as.x); as.y = fmaf(sv, w.y, as.y);
        as.z = fmaf(sv, w.z, as.z); as.w = fmaf(sv, w.w, as.w);
    }
    float* mc = &M[(size_t)(b * 16 + h) * Dn + j];
    float* ms = &M[(size_t)(b * 16 + 8 + h) * Dn + j];
    atomicAdd(mc + 0, ac.x); atomicAdd(mc + 1, ac.y);
    atomicAdd(mc + 2, ac.z); atomicAdd(mc + 3, ac.w);
    atomicAdd(ms + 0, as.x); atomicAdd(ms + 1, as.y);
    atomicAdd(ms + 2, as.z); atomicAdd(ms + 3, as.w);
}

// ---------------- block LayerNorm stats helper ----------------
__device__ inline void block_ln_stats(float lsum, float lsq, float* red,
                                      float& mean, float& rstd) {
    #pragma unroll
    for (int off = 32; off; off >>= 1) {
        lsum += __shfl_xor(lsum, off);
        lsq  += __shfl_xor(lsq, off);
    }
    const int wid = threadIdx.x >> 6;
    if ((threadIdx.x & 63) == 0) { red[wid * 2] = lsum; red[wid * 2 + 1] = lsq; }
    __syncthreads();
    if (threadIdx.x == 0) {
        float s  = red[0] + red[2] + red[4] + red[6];
        float ss = red[1] + red[3] + red[5] + red[7];
        float m = s * (1.0f / Dn);
        red[8] = m;
        red[9] = rsqrtf(ss * (1.0f / Dn) - m * m + 1e-5f);
    }
    __syncthreads();
    mean = red[8];
    rstd = red[9];
}

// ---------------- x = LN(residual + rank16-combine + bf) -> bf16 hi/lo pair ----------------
__global__ void k_x(const float* __restrict__ residual, const float* __restrict__ bf,
                    const float* __restrict__ g1, const float* __restrict__ b1,
                    const float* __restrict__ ws, unsigned short* __restrict__ Xp) {
    __shared__ float lcoef[16];
    __shared__ float red[12];
    const int bq = blockIdx.x;       // b*SQ + q
    const int b = bq >> 10;
    const int tid = threadIdx.x;
    if (tid < 8) {
        float dinv = 1.0f / (ws[OFF_DEN + bq * Hn + tid] + 1e-6f);
        lcoef[tid]     = ws[OFF_CQ + bq * Hn + tid] * dinv;
        lcoef[8 + tid] = ws[OFF_SQ + bq * Hn + tid] * dinv;
    }
    __syncthreads();
    const int j = tid * 4;
    float4 acc = *(const float4*)&bf[j];
    const float* Mp = ws + OFF_M + (size_t)b * 16 * Dn + j;
    #pragma unroll
    for (int t = 0; t < 16; ++t) {
        float cf = lcoef[t];
        float4 m4 = *(const float4*)&Mp[(size_t)t * Dn];
        acc.x = fmaf(cf, m4.x, acc.x); acc.y = fmaf(cf, m4.y, acc.y);
        acc.z = fmaf(cf, m4.z, acc.z); acc.w = fmaf(cf, m4.w, acc.w);
    }
    float4 r = *(const float4*)&residual[(size_t)bq * Dn + j];
    acc.x += r.x; acc.y += r.y; acc.z += r.z; acc.w += r.w;
    float lsum = acc.x + acc.y + acc.z + acc.w;
    float lsq = acc.x * acc.x + acc.y * acc.y + acc.z * acc.z + acc.w * acc.w;
    float mean, rstd;
    block_ln_stats(lsum, lsq, red, mean, rstd);
    float4 g = *(const float4*)&g1[j];
    float4 be = *(const float4*)&b1[j];
    float o[4];
    o[0] = (acc.x - mean) * rstd * g.x + be.x;
    o[1] = (acc.y - mean) * rstd * g.y + be.y;
    o[2] = (acc.z - mean) * rstd * g.z + be.z;
    o[3] = (acc.w - mean) * rstd * g.w + be.w;
    ushort4 hi, lo;
    unsigned short* hp = (unsigned short*)&hi;
    unsigned short* lp = (unsigned short*)&lo;
    #pragma unroll
    for (int u = 0; u < 4; ++u) {
        hp[u] = f2bf(o[u]);
        lp[u] = f2bf(o[u] - bf2f(hp[u]));
    }
    *(ushort4*)&Xp[(size_t)bq * 2048 + j] = hi;
    *(ushort4*)&Xp[(size_t)bq * 2048 + 1024 + j] = lo;
}

// ---------------- fused 3-term split-bf16 MFMA GEMM, counted-vmcnt pipeline ----------------
// C = act( (Ah+Al) @ (Wh+Wl)^T + bias ), terms Ah*Wh + Al*Wh + Ah*Wl.
// Half-k (32-wide) double-buffer; STAGE(next) -> vmcnt(8) -> barrier ->
// ds_read+48x2 MFMA -> barrier. Prefetch stays in flight across barriers.
// sched_barrier(0) after/before the raw s_barriers pins the LDS reads inside
// the barrier-protected window (raw s_barrier is not an LLVM memory fence).
__global__ __launch_bounds__(256) void gemm_split(const unsigned short* __restrict__ Ap,
                                                  const unsigned short* __restrict__ Wp,
                                                  const float* __restrict__ bias,
                                                  unsigned short* __restrict__ Cp,
                                                  unsigned short* __restrict__ Cb, int mode) {
    __shared__ __align__(16) unsigned short buf[2][4][128 * 32];
    const int t = threadIdx.x;
    // XCD-locality swizzle: XCD c (= orig&7) owns m-blocks [8c,8c+8)
    const int orig = blockIdx.x;
    const int c = orig & 7, g = orig >> 3;
    const int m0 = (c * 8 + (g & 7)) * 128;
    const int n0 = (g >> 3) * 128;

    const int w = t >> 6;          // wave 0..3
    const int wm = (w >> 1) * 64;
    const int wn = (w & 1) * 64;
    const int l15 = t & 15;
    const int kq = (t >> 4) & 3;

    const int tr2 = t >> 2;        // staging row 0..63
    const int tc2 = (t & 3) * 8;   // staging col (elements, within 32)

    f32x4 acc[4][4];
    #pragma unroll
    for (int m = 0; m < 4; ++m)
        #pragma unroll
        for (int n = 0; n < 4; ++n)
            acc[m][n] = (f32x4){0.f, 0.f, 0.f, 0.f};

#define STAGE(pp, kh) do {                                                          \
        const int k0_ = (kh) * 32;                                                  \
        _Pragma("unroll")                                                           \
        for (int i_ = 0; i_ < 2; ++i_) {                                            \
            const int row_ = i_ * 64 + tr2;                                         \
            gld16(Ap + (size_t)(m0 + row_) * 2048 + k0_ + tc2,                      \
                  &buf[pp][0][row_ * 32 + tc2]);                                    \
            gld16(Ap + (size_t)(m0 + row_) * 2048 + 1024 + k0_ + tc2,               \
                  &buf[pp][1][row_ * 32 + tc2]);                                    \
            gld16(Wp + (size_t)(n0 + row_) * 2048 + k0_ + tc2,                      \
                  &buf[pp][2][row_ * 32 + tc2]);                                    \
            gld16(Wp + (size_t)(n0 + row_) * 2048 + 1024 + k0_ + tc2,               \
                  &buf[pp][3][row_ * 32 + tc2]);                                    \
        }                                                                           \
    } while (0)

    STAGE(0, 0);
    for (int kh = 0; kh < 32; ++kh) {
        const int cur = kh & 1;
        if (kh < 31) {
            STAGE(cur ^ 1, kh + 1);    // 8 loads/thread stay in flight
            asm volatile("s_waitcnt vmcnt(8)" ::: "memory");   // cur's 8 landed
        } else {
            asm volatile("s_waitcnt vmcnt(0)" ::: "memory");
        }
        __builtin_amdgcn_s_barrier();  // all waves' cur loads landed
        __builtin_amdgcn_sched_barrier(0);   // keep LDS reads below the barrier
        short8 afh[4], afl[4], bfh[4], bfl[4];
        #pragma unroll
        for (int m = 0; m < 4; ++m) {
            const int ro = (wm + m * 16 + l15) * 32 + kq * 8;
            afh[m] = *(const short8*)&buf[cur][0][ro];
            afl[m] = *(const short8*)&buf[cur][1][ro];
        }
        #pragma unroll
        for (int n = 0; n < 4; ++n) {
            const int ro = (wn + n * 16 + l15) * 32 + kq * 8;
            bfh[n] = *(const short8*)&buf[cur][2][ro];
            bfl[n] = *(const short8*)&buf[cur][3][ro];
        }
        #pragma unroll
        for (int m = 0; m < 4; ++m)
            #pragma unroll
            for (int n = 0; n < 4; ++n) {
                acc[m][n] = __builtin_amdgcn_mfma_f32_16x16x32_bf16(
                    afh[m], bfh[n], acc[m][n], 0, 0, 0);
                acc[m][n] = __builtin_amdgcn_mfma_f32_16x16x32_bf16(
                    afl[m], bfh[n], acc[m][n], 0, 0, 0);
                acc[m][n] = __builtin_amdgcn_mfma_f32_16x16x32_bf16(
                    afh[m], bfl[n], acc[m][n], 0, 0, 0);
            }
        __builtin_amdgcn_sched_barrier(0);   // keep LDS reads above the barrier
        __builtin_amdgcn_s_barrier();  // readers of buf[cur] done; next iter overwrites it
    }
#undef STAGE

    // epilogue
    #pragma unroll
    for (int n = 0; n < 4; ++n) {
        const int col = n0 + wn + n * 16 + l15;
        const float bv = bias[col];
        #pragma unroll
        for (int m = 0; m < 4; ++m) {
            #pragma unroll
            for (int r = 0; r < 4; ++r) {
                const int row = m0 + wm + m * 16 + kq * 4 + r;
                float cc = acc[m][n][r] + bv;
                if (mode == 0) {
                    cc = fmaxf(cc, 0.f);
                    unsigned short hi = f2bf(cc);
                    unsigned short lo = f2bf(cc - bf2f(hi));
                    Cp[(size_t)row * 2048 + col] = hi;
                    Cp[(size_t)row * 2048 + 1024 + col] = lo;
                } else {
                    Cb[(size_t)row * 1024 + col] = f2bf(cc);
                }
            }
        }
    }
}

// ---------------- out = LN(x + mlp_out, g2, b2) ----------------
__global__ void k_final(const unsigned short* __restrict__ Xp,
                        const unsigned short* __restrict__ Y,
                        const float* __restrict__ g2, const float* __restrict__ b2,
                        float* __restrict__ out) {
    __shared__ float red[12];
    const int bq = blockIdx.x;
    const int tid = threadIdx.x;
    const int j = tid * 4;
    ushort4 xh = *(const ushort4*)&Xp[(size_t)bq * 2048 + j];
    ushort4 xl = *(const ushort4*)&Xp[(size_t)bq * 2048 + 1024 + j];
    ushort4 yv = *(const ushort4*)&Y[(size_t)bq * 1024 + j];
    float xv[4];
    xv[0] = bf2f(xh.x) + bf2f(xl.x) + bf2f(yv.x);
    xv[1] = bf2f(xh.y) + bf2f(xl.y) + bf2f(yv.y);
    xv[2] = bf2f(xh.z) + bf2f(xl.z) + bf2f(yv.z);
    xv[3] = bf2f(xh.w) + bf2f(xl.w) + bf2f(yv.w);
    float lsum = xv[0] + xv[1] + xv[2] + xv[3];
    float lsq = xv[0]*xv[0] + xv[1]*xv[1] + xv[2]*xv[2] + xv[3]*xv[3];
    float mean, rstd;
    block_ln_stats(lsum, lsq, red, mean, rstd);
    float4 g = *(const float4*)&g2[j];
    float4 be = *(const float4*)&b2[j];
    float4 o;
    o.x = (xv[0] - mean) * rstd * g.x + be.x;
    o.y = (xv[1] - mean) * rstd * g.y + be.y;
    o.z = (xv[2] - mean) * rstd * g.z + be.z;
    o.w = (xv[3] - mean) * rstd * g.w + be.w;
    *(float4*)&out[(size_t)bq * Dn + j] = o;
}

extern "C" void kernel_launch(void* const* d_in, const int* in_sizes, int n_in,
                              void* d_out, int out_size, void* d_ws, size_t ws_size,
                              hipStream_t stream) {
    const float* key_in   = (const float*)d_in[0];
    const float* query_in = (const float*)d_in[1];
    const float* value_in = (const float*)d_in[2];
    const float* residual = (const float*)d_in[3];
    const float* Wk  = (const float*)d_in[4];
    const float* Wq  = (const float*)d_in[5];
    const float* Wv  = (const float*)d_in[6];
    const float* Wf  = (const float*)d_in[7];
    const float* bf  = (const float*)d_in[8];
    const float* g1  = (const float*)d_in[9];
    const float* b1  = (const float*)d_in[10];
    const float* Wm1 = (const float*)d_in[11];
    const float* bm1 = (const float*)d_in[12];
    const float* Wm2 = (const float*)d_in[13];
    const float* bm2 = (const float*)d_in[14];
    const float* Wm3 = (const float*)d_in[15];
    const float* bm3 = (const float*)d_in[16];
    const float* g2  = (const float*)d_in[17];
    const float* b2  = (const float*)d_in[18];
    float* ws  = (float*)d_ws;
    float* out = (float*)d_out;

    unsigned short* Xp  = (unsigned short*)(ws + OFF_X);
    unsigned short* H1p = (unsigned short*)(ws + OFF_H1);   // layer-1 output pair
    unsigned short* H2p = (unsigned short*)out;             // layer-2 output pair (d_out scratch)
    unsigned short* Yb  = (unsigned short*)(ws + OFF_H1);   // layer-3 bf16 output (over H1p, dead)
    unsigned short* WT  = (unsigned short*)(ws + OFF_WT);
    float* Pcp = ws + OFF_X;                 // P partials live in X region pre-k_x
    float* Psp = ws + OFF_X + 1048576;

    // prep: trig + weight split + zero atomic targets (ws poisoned 0xAA pre-launch)
    k_prep<<<1488, 256, 0, stream>>>(key_in, query_in, Wk, Wq, Wm1, Wm2, Wm3, ws, WT);
    k_pd<<<1024, 256, 0, stream>>>(value_in, ws, Pcp, Psp, ws + OFF_DEN);
    k_cv<<<dim3(64, 16), 128, 0, stream>>>(Pcp, Psp, Wv, ws + OFF_CV, ws + OFF_SV);
    k_m<<<dim3(64, 4), 256, 0, stream>>>(ws + OFF_CV, ws + OFF_SV, Wf, ws + OFF_M);
    k_x<<<8192, 256, 0, stream>>>(residual, bf, g1, b1, ws, Xp);

    // MLP via fused split-bf16 MFMA GEMMs (counted-vmcnt pipeline)
    gemm_split<<<512, 256, 0, stream>>>(Xp, WT, bm1, H1p, nullptr, 0);
    gemm_split<<<512, 256, 0, stream>>>(H1p, WT + 2097152, bm2, H2p, nullptr, 0);
    gemm_split<<<512, 256, 0, stream>>>(H2p, WT + 2 * 2097152, bm3, nullptr, Yb, 1);
    k_final<<<8192, 256, 0, stream>>>(Xp, Yb, g2, b2, out);
}